// Round 13
// baseline (809.040 us; speedup 1.0000x reference)
//
#include <hip/hip_runtime.h>
#include <hip/hip_bf16.h>

typedef __bf16 bf16_t;
typedef __bf16 bf16x8 __attribute__((ext_vector_type(8)));
typedef __bf16 bf16x4 __attribute__((ext_vector_type(4)));
typedef __bf16 bf16x2 __attribute__((ext_vector_type(2)));
typedef float  f32x4  __attribute__((ext_vector_type(4)));
typedef float  f32x2  __attribute__((ext_vector_type(2)));
typedef float  f32x8  __attribute__((ext_vector_type(8)));

static __device__ __forceinline__ void gload_lds16(const void* g, void* l) {
  __builtin_amdgcn_global_load_lds((const __attribute__((address_space(1))) void*)g,
                                   (__attribute__((address_space(3))) void*)l, 16, 0, 0);
}

// LDS chunk swizzle for [rows][32] bf16 tiles: chunk' = chunk ^ ((row>>1)&3).
// Per-batch dead flags: bflag[b]==1 once all 1024 positions of batch b have
// halted (hp>=1) AND uw==0 -> that batch's remaining compute is provably
// dead w.r.t. prev (attention never mixes across batches). Bit-exact skip.

// ------------------------------------------------------------------
// GEMM  C = A*B^T (+bias, relu opt), bf16 out. 128x128 tile, BK=32,
// 4 waves, 2-phase dbuf. VT=true (QKV): output tiles with n0>=1024
// are the V columns -> written TRANSPOSED into vt (per (b,h): d x key).
// M-tiles (128 rows) align with batches (1024 rows): batch = bid.x>>3.
// ------------------------------------------------------------------
template <bool RELU, bool VT>
__global__ __launch_bounds__(256)
void gemm_bt(const bf16_t* __restrict__ A, const bf16_t* __restrict__ B,
             const float* __restrict__ bias, bf16_t* __restrict__ C,
             bf16_t* __restrict__ vt, int M, int N, int K,
             const int* __restrict__ bflag)
{
  if (bflag[blockIdx.x >> 3]) return;
  __shared__ bf16_t As[2][128 * 32];
  __shared__ bf16_t Bs[2][128 * 32];
  const int tid = threadIdx.x;
  const int lane = tid & 63, wave = tid >> 6;
  const int wr = (wave >> 1) * 64, wc = (wave & 1) * 64;
  const int lr = lane & 15, lg = lane >> 4;
  const int m0 = blockIdx.x * 128, n0 = blockIdx.y * 128;

  const bf16_t* Ab = A + (size_t)m0 * K;
  const bf16_t* Bb = B + (size_t)n0 * K;

  f32x4 acc[4][4] = {};

  const int r0 = tid >> 2;
  const int c0 = (((tid & 3) ^ ((r0 >> 1) & 3)) * 8);
  const int lsw = (lg ^ ((lr >> 1) & 3)) * 8;

  auto stage = [&](int buf, int kk) {
    gload_lds16(Ab + (size_t)r0 * K + kk + c0,        &As[buf][tid * 8]);
    gload_lds16(Bb + (size_t)r0 * K + kk + c0,        &Bs[buf][tid * 8]);
    gload_lds16(Ab + (size_t)(r0 + 64) * K + kk + c0, &As[buf][(tid + 256) * 8]);
    gload_lds16(Bb + (size_t)(r0 + 64) * K + kk + c0, &Bs[buf][(tid + 256) * 8]);
  };

  stage(0, 0);
  __syncthreads();

  const int nk = K >> 5;
  for (int t = 0; t < nk; ++t) {
    const int buf = t & 1;
    if (t + 1 < nk) stage(buf ^ 1, (t + 1) * 32);
    bf16x8 af[4], bfr[4];
#pragma unroll
    for (int i = 0; i < 4; i++) af[i]  = *(const bf16x8*)(&As[buf][(wr + i * 16 + lr) * 32 + lsw]);
#pragma unroll
    for (int j = 0; j < 4; j++) bfr[j] = *(const bf16x8*)(&Bs[buf][(wc + j * 16 + lr) * 32 + lsw]);
#pragma unroll
    for (int i = 0; i < 4; i++)
#pragma unroll
      for (int j = 0; j < 4; j++)
        acc[i][j] = __builtin_amdgcn_mfma_f32_16x16x32_bf16(af[i], bfr[j], acc[i][j], 0, 0, 0);
    __syncthreads();
  }

  const int rg = (lane >> 4) * 4;
  if (VT && n0 >= 1024) {
#pragma unroll
    for (int j = 0; j < 4; j++) {
      const int col = n0 + wc + j * 16 + lr;      // 1024..1535
      const float bv = bias[col];
      const int hd = col - 1024;                  // h*64 + d
#pragma unroll
      for (int i = 0; i < 4; i++) {
        const int row0 = m0 + wr + i * 16 + rg;   // token index
        const int bb = row0 >> 10, key = row0 & 1023;
        bf16x4 q;
#pragma unroll
        for (int r = 0; r < 4; r++) q[r] = (bf16_t)(acc[i][j][r] + bv);
        *(bf16x4*)(vt + ((size_t)bb * 512 + hd) * 1024 + key) = q;
      }
    }
  } else {
#pragma unroll
    for (int j = 0; j < 4; j++) {
      const int col = n0 + wc + j * 16 + lr;
      const float bv = bias ? bias[col] : 0.0f;
#pragma unroll
      for (int i = 0; i < 4; i++) {
#pragma unroll
        for (int r = 0; r < 4; r++) {
          const int row = m0 + wr + i * 16 + rg + r;
          float v = acc[i][j][r] + bv;
          if (RELU) v = fmaxf(v, 0.0f);
          C[(size_t)row * N + col] = (bf16_t)v;
        }
      }
    }
  }
}

// ------------------------------------------------------------------
// GEMM 128x128, 512 threads / 8 waves (2x4), wave = 64x32, 2-phase
// dbuf, bf16 output, split-K via gridDim.z (z-half k writes buffer
// Ck; bias folded into half 0 only). O-proj (z=2), FFN2 (z=2).
// ------------------------------------------------------------------
__global__ __launch_bounds__(512)
void gemm_bt512(const bf16_t* __restrict__ A, const bf16_t* __restrict__ B,
                const float* __restrict__ bias, bf16_t* __restrict__ C0,
                bf16_t* __restrict__ C1, int M, int N, int Kfull, int Keff,
                const int* __restrict__ bflag)
{
  if (bflag[blockIdx.x >> 3]) return;
  __shared__ bf16_t As[2][128 * 32];
  __shared__ bf16_t Bs[2][128 * 32];
  const int tid = threadIdx.x;
  const int lane = tid & 63, wave = tid >> 6;
  const int wr = (wave >> 2) * 64, wc = (wave & 3) * 32;
  const int lr = lane & 15, lg = lane >> 4;
  const int m0 = blockIdx.x * 128, n0 = blockIdx.y * 128;
  const int kb = blockIdx.z;

  const bf16_t* Ab = A + (size_t)m0 * Kfull + (size_t)kb * Keff;
  const bf16_t* Bb = B + (size_t)n0 * Kfull + (size_t)kb * Keff;
  bf16_t* C = kb ? C1 : C0;

  f32x4 acc[4][2] = {};

  const int r0 = tid >> 2;
  const int c0 = (((tid & 3) ^ ((r0 >> 1) & 3)) * 8);
  const int lsw = (lg ^ ((lr >> 1) & 3)) * 8;

  auto stage = [&](int buf, int kk) {
    gload_lds16(Ab + (size_t)r0 * Kfull + kk + c0, &As[buf][tid * 8]);
    gload_lds16(Bb + (size_t)r0 * Kfull + kk + c0, &Bs[buf][tid * 8]);
  };

  stage(0, 0);
  __syncthreads();

  const int nk = Keff >> 5;
  for (int t = 0; t < nk; ++t) {
    const int buf = t & 1;
    if (t + 1 < nk) stage(buf ^ 1, (t + 1) * 32);
    bf16x8 af[4], bfr[2];
#pragma unroll
    for (int i = 0; i < 4; i++) af[i]  = *(const bf16x8*)(&As[buf][(wr + i * 16 + lr) * 32 + lsw]);
#pragma unroll
    for (int j = 0; j < 2; j++) bfr[j] = *(const bf16x8*)(&Bs[buf][(wc + j * 16 + lr) * 32 + lsw]);
#pragma unroll
    for (int i = 0; i < 4; i++)
#pragma unroll
      for (int j = 0; j < 2; j++)
        acc[i][j] = __builtin_amdgcn_mfma_f32_16x16x32_bf16(af[i], bfr[j], acc[i][j], 0, 0, 0);
    __syncthreads();
  }

  const int rg = (lane >> 4) * 4;
#pragma unroll
  for (int j = 0; j < 2; j++) {
    const int col = n0 + wc + j * 16 + lr;
    const float bv = (bias && kb == 0) ? bias[col] : 0.0f;
#pragma unroll
    for (int i = 0; i < 4; i++) {
#pragma unroll
      for (int r = 0; r < 4; r++) {
        const int row = m0 + wr + i * 16 + rg + r;
        C[(size_t)row * N + col] = (bf16_t)(acc[i][j][r] + bv);
      }
    }
  }
}

// ------------------------------------------------------------------
// Flash attention (swapped QK^T): S^T = mfma(K,Q), per-lane scalar
// online softmax with defer-max, cvt_pk P-packing. K tiles LDS-staged
// (dbuf + XOR swizzle); V^T fragments read DIRECTLY from global
// (L2-resident, 128KB/(b,h) re-read by 8 q-blocks — m169 pattern:
// staging L2-fit data is pure overhead). LDS 33.8KB -> 4 blocks/CU.
// ------------------------------------------------------------------
__global__ __launch_bounds__(512)
void k_attn(const bf16_t* __restrict__ qkv, const bf16_t* __restrict__ vt,
            bf16_t* __restrict__ out, const int* __restrict__ bflag)
{
  if (bflag[blockIdx.x >> 3]) return;
  const int bh = blockIdx.x;
  const int qt = blockIdx.y;
  const int b = bh >> 3, h = bh & 7;
  const int tid = threadIdx.x, lane = tid & 63, wave = tid >> 6;
  const int lr = lane & 15, lg = lane >> 4;

  __shared__ bf16_t Ks[2][4096];
  __shared__ bf16_t Pl[8][16][68];

  const size_t RS = 1536;
  const bf16_t* Qb = qkv + ((size_t)(b * 1024 + qt * 128)) * RS + h * 64;
  const bf16_t* Kb = qkv + ((size_t)(b * 1024)) * RS + 512 + h * 64;
  const bf16_t* Vt = vt + (size_t)bh * 64 * 1024;

  const float SC = 0.125f * 1.4426950408889634f;
  bf16x8 qf[2];
#pragma unroll
  for (int ks = 0; ks < 2; ks++) {
    bf16x8 q = *(const bf16x8*)(Qb + (size_t)(wave * 16 + lr) * RS + lg * 8 + ks * 32);
#pragma unroll
    for (int u = 0; u < 8; u++) q[u] = (bf16_t)((float)q[u] * SC);
    qf[ks] = q;
  }

  f32x4 o[4] = {};
  float m_ = -1e30f, ls_ = 0.0f;     // per-lane: q-row = wave*16 + lane&15

  // stage K tile only (8KB): 512 threads x 1 chunk of 16B
  auto stage = [&](int buf, int kv) {
    const int c = tid;
    const int r = c >> 3;
    const int ce = (c & 7) * 8;
    const int cs = ce ^ ((r & 7) << 3);
    gload_lds16(Kb + (size_t)(kv * 64 + r) * RS + cs, &Ks[buf][c * 8]);
  };

  stage(0, 0);
  __syncthreads();

  const int sw = (lr & 7) << 3;

  for (int kv = 0; kv < 16; kv++) {
    const int buf = kv & 1;
    if (kv < 15) stage(buf ^ 1, kv + 1);

    // V^T fragments: independent 16B global loads (L2-hit), issued
    // here so their latency hides under QK^T + softmax.
    bf16x8 vb[2][4];
#pragma unroll
    for (int ks = 0; ks < 2; ks++)
#pragma unroll
      for (int j = 0; j < 4; j++)
        vb[ks][j] = *(const bf16x8*)(Vt + (size_t)(j * 16 + lr) * 1024 + kv * 64 + lg * 8 + ks * 32);

    f32x4 sfr[4];
    __builtin_amdgcn_s_setprio(1);
#pragma unroll
    for (int j = 0; j < 4; j++) {
      f32x4 z = {};
#pragma unroll
      for (int ks = 0; ks < 2; ks++) {
        bf16x8 kf = *(const bf16x8*)(&Ks[buf][(j * 16 + lr) * 64 + ((lg * 8 + ks * 32) ^ sw)]);
        z = __builtin_amdgcn_mfma_f32_16x16x32_bf16(kf, qf[ks], z, 0, 0, 0);
      }
      sfr[j] = z;
    }
    __builtin_amdgcn_s_setprio(0);

    float px = sfr[0][0];
#pragma unroll
    for (int j = 0; j < 4; j++)
#pragma unroll
      for (int r = 0; r < 4; r++) px = fmaxf(px, sfr[j][r]);
    if (!__all(px <= m_ + 8.0f)) {
      float mx = fmaxf(px, __shfl_xor(px, 16, 64));
      mx = fmaxf(mx, __shfl_xor(mx, 32, 64));
      mx = fmaxf(mx, m_);
      const float al = __builtin_amdgcn_exp2f(m_ - mx);
      m_ = mx;
      ls_ *= al;
      float aq[4];
#pragma unroll
      for (int r = 0; r < 4; r++) aq[r] = __shfl(al, lg * 4 + r, 64);
#pragma unroll
      for (int j = 0; j < 4; j++)
#pragma unroll
        for (int r = 0; r < 4; r++) o[j][r] *= aq[r];
    }

    float ps = 0.0f;
#pragma unroll
    for (int j = 0; j < 4; j++) {
      const float p0 = __builtin_amdgcn_exp2f(sfr[j][0] - m_);
      const float p1 = __builtin_amdgcn_exp2f(sfr[j][1] - m_);
      const float p2 = __builtin_amdgcn_exp2f(sfr[j][2] - m_);
      const float p3 = __builtin_amdgcn_exp2f(sfr[j][3] - m_);
      ps += (p0 + p1) + (p2 + p3);
      unsigned lo, hi;
      asm("v_cvt_pk_bf16_f32 %0, %1, %2" : "=v"(lo) : "v"(p0), "v"(p1));
      asm("v_cvt_pk_bf16_f32 %0, %1, %2" : "=v"(hi) : "v"(p2), "v"(p3));
      uint2 w; w.x = lo; w.y = hi;
      *(uint2*)(&Pl[wave][lr][j * 16 + lg * 4]) = w;
    }
    ls_ += ps;

    __builtin_amdgcn_s_setprio(1);
#pragma unroll
    for (int ks = 0; ks < 2; ks++) {
      bf16x8 pa = *(const bf16x8*)(&Pl[wave][lr][lg * 8 + ks * 32]);
#pragma unroll
      for (int j = 0; j < 4; j++)
        o[j] = __builtin_amdgcn_mfma_f32_16x16x32_bf16(pa, vb[ks][j], o[j], 0, 0, 0);
    }
    __builtin_amdgcn_s_setprio(0);

    __syncthreads();
  }

  ls_ += __shfl_xor(ls_, 16, 64);
  ls_ += __shfl_xor(ls_, 32, 64);
  float lsq[4];
#pragma unroll
  for (int r = 0; r < 4; r++) lsq[r] = __shfl(ls_, lg * 4 + r, 64);

  const size_t orow = (size_t)(b * 1024 + qt * 128 + wave * 16 + lg * 4);
#pragma unroll
  for (int j = 0; j < 4; j++)
#pragma unroll
    for (int r = 0; r < 4; r++)
      out[(orow + r) * 512 + h * 64 + j * 16 + lr] = (bf16_t)(o[j][r] / lsq[r]);
}

// ------------------------------------------------------------------
// Step 0 top: x = state + pos + ts[0] (bf16 out only — xB doubles as
// the LN1 residual); p = sigmoid(x . p_w + p_b); ACT halting update.
// ------------------------------------------------------------------
__global__ __launch_bounds__(256)
void k_poshalt(const float* __restrict__ state, bf16_t* __restrict__ xbf,
               const float* __restrict__ pos, const float* __restrict__ ts,
               const float* __restrict__ pw, const float* __restrict__ pb,
               float* __restrict__ hp, float* __restrict__ rem, float* __restrict__ uw)
{
  const int row = blockIdx.x;
  const int l = row & 1023;
  const int t = threadIdx.x;
  const size_t base = (size_t)row * 512;
  float v0 = state[base + t]       + pos[l * 512 + t]       + ts[t];
  float v1 = state[base + 256 + t] + pos[l * 512 + 256 + t] + ts[256 + t];
  xbf[base + t] = (bf16_t)v0; xbf[base + 256 + t] = (bf16_t)v1;

  float d = v0 * pw[t] + v1 * pw[256 + t];
#pragma unroll
  for (int mk = 1; mk < 64; mk <<= 1) d += __shfl_xor(d, mk, 64);
  __shared__ float part[4];
  if ((t & 63) == 0) part[t >> 6] = d;
  __syncthreads();
  if (t == 0) {
    const float z = part[0] + part[1] + part[2] + part[3] + pb[0];
    const float p = 1.0f / (1.0f + expf(-z));
    float h = 0.0f, rm = 0.0f;
    const float cond = p;
    const float nh = (cond > 0.9f) ? 1.0f : 0.0f;
    const float st = (cond <= 0.9f) ? 1.0f : 0.0f;
    h += p * st;
    rm += nh * (1.0f - h);
    h += nh * rm;
    hp[row] = h; rem[row] = rm;
    uw[row] = p * st + nh * rm;
  }
}

// ------------------------------------------------------------------
// Post-attn LN: y = LayerNorm(xB + o0 + o1)  (all bf16; o0/o1 are the
// O-proj split-K halves); write y bf16 only.
// ------------------------------------------------------------------
__global__ __launch_bounds__(256)
void k_addln1(const bf16_t* __restrict__ xb, const bf16_t* __restrict__ o0,
              const bf16_t* __restrict__ o1,
              const float* __restrict__ g, const float* __restrict__ be,
              bf16_t* __restrict__ ybf, const int* __restrict__ bflag)
{
  if (bflag[blockIdx.x >> 10]) return;
  const int row = blockIdx.x, t = threadIdx.x;
  const size_t base = (size_t)row * 512 + 2 * t;
  bf16x2 xv = *(const bf16x2*)(xb + base);
  bf16x2 a0 = *(const bf16x2*)(o0 + base);
  bf16x2 a1 = *(const bf16x2*)(o1 + base);
  const float v0 = (float)xv[0] + (float)a0[0] + (float)a1[0];
  const float v1 = (float)xv[1] + (float)a0[1] + (float)a1[1];
  float s1 = v0 + v1, s2 = v0 * v0 + v1 * v1;
#pragma unroll
  for (int mk = 1; mk < 64; mk <<= 1) { s1 += __shfl_xor(s1, mk, 64); s2 += __shfl_xor(s2, mk, 64); }
  __shared__ float p1[4], p2[4];
  if ((t & 63) == 0) { p1[t >> 6] = s1; p2[t >> 6] = s2; }
  __syncthreads();
  s1 = p1[0] + p1[1] + p1[2] + p1[3];
  s2 = p2[0] + p2[1] + p2[2] + p2[3];
  const float mean = s1 * (1.0f / 512.0f);
  const float var  = s2 * (1.0f / 512.0f) - mean * mean;
  const float ri = rsqrtf(var + 1e-5f);
  f32x2 gv = *(const f32x2*)(g + 2 * t);
  f32x2 bv = *(const f32x2*)(be + 2 * t);
  bf16x2 yo;
  yo[0] = (bf16_t)((v0 - mean) * ri * gv[0] + bv[0]);
  yo[1] = (bf16_t)((v1 - mean) * ri * gv[1] + bv[1]);
  *(bf16x2*)(ybf + base) = yo;
}

// ------------------------------------------------------------------
// Fused bottom-of-step: y = LN(x1B + pA + pB) (bf16 inputs);
// prev = y*uw + prev*(1-uw); then NEXT step's pos/ts add + halting
// (writes only xB, the bf16 state that doubles as next residual).
// ------------------------------------------------------------------
template <bool LAST>
__global__ __launch_bounds__(256)
void k_lnhalt(const bf16_t* __restrict__ x1b, const bf16_t* __restrict__ pA,
              const bf16_t* __restrict__ pB,
              const float* __restrict__ g, const float* __restrict__ be,
              const float* __restrict__ pos, const float* __restrict__ ts, int nstep,
              const float* __restrict__ pw, const float* __restrict__ pb,
              bf16_t* __restrict__ xbf,
              float* __restrict__ hp, float* __restrict__ rem, float* __restrict__ uw,
              float* __restrict__ prev, int step, const int* __restrict__ bflag)
{
  if (bflag[blockIdx.x >> 10]) return;
  const int row = blockIdx.x, t = threadIdx.x;
  const int l = row & 1023;
  const size_t base = (size_t)row * 512 + 2 * t;
  bf16x2 xv = *(const bf16x2*)(x1b + base);
  bf16x2 av = *(const bf16x2*)(pA + base);
  bf16x2 bv2 = *(const bf16x2*)(pB + base);
  const float a0 = (float)xv[0] + (float)av[0] + (float)bv2[0];
  const float a1 = (float)xv[1] + (float)av[1] + (float)bv2[1];
  float s1 = a0 + a1, s2 = a0 * a0 + a1 * a1;
#pragma unroll
  for (int mk = 1; mk < 64; mk <<= 1) { s1 += __shfl_xor(s1, mk, 64); s2 += __shfl_xor(s2, mk, 64); }
  __shared__ float p1[4], p2[4], pd[4];
  if ((t & 63) == 0) { p1[t >> 6] = s1; p2[t >> 6] = s2; }
  __syncthreads();
  s1 = p1[0] + p1[1] + p1[2] + p1[3];
  s2 = p2[0] + p2[1] + p2[2] + p2[3];
  const float mean = s1 * (1.0f / 512.0f);
  const float var  = s2 * (1.0f / 512.0f) - mean * mean;
  const float ri = rsqrtf(var + 1e-5f);
  f32x2 gv = *(const f32x2*)(g + 2 * t);
  f32x2 bev = *(const f32x2*)(be + 2 * t);
  const float y0 = (a0 - mean) * ri * gv[0] + bev[0];
  const float y1 = (a1 - mean) * ri * gv[1] + bev[1];

  const float w = uw[row];
  if (step == 0) {
    f32x2 np; np[0] = y0 * w; np[1] = y1 * w;
    *(f32x2*)(prev + base) = np;
  } else if (w != 0.0f) {
    f32x2 pv = *(const f32x2*)(prev + base);
    f32x2 np;
    np[0] = y0 * w + pv[0] * (1.0f - w);
    np[1] = y1 * w + pv[1] * (1.0f - w);
    *(f32x2*)(prev + base) = np;
  }

  if (LAST) return;

  f32x2 pp = *(const f32x2*)(pos + l * 512 + 2 * t);
  f32x2 tv = *(const f32x2*)(ts + nstep * 512 + 2 * t);
  const float v0 = y0 + pp[0] + tv[0];
  const float v1 = y1 + pp[1] + tv[1];
  bf16x2 xo; xo[0] = (bf16_t)v0; xo[1] = (bf16_t)v1;
  *(bf16x2*)(xbf + base) = xo;

  f32x2 wv = *(const f32x2*)(pw + 2 * t);
  float d = v0 * wv[0] + v1 * wv[1];
#pragma unroll
  for (int mk = 1; mk < 64; mk <<= 1) d += __shfl_xor(d, mk, 64);
  if ((t & 63) == 0) pd[t >> 6] = d;
  __syncthreads();
  if (t == 0) {
    const float z = pd[0] + pd[1] + pd[2] + pd[3] + pb[0];
    const float p = 1.0f / (1.0f + expf(-z));
    float h  = hp[row];
    float rm = rem[row];
    const float still0 = (h < 1.0f) ? 1.0f : 0.0f;
    const float cond = h + p * still0;
    const float nh = (cond > 0.9f) ? still0 : 0.0f;
    const float st = (cond <= 0.9f) ? still0 : 0.0f;
    h += p * st;
    rm += nh * (1.0f - h);
    h += nh * rm;
    hp[row] = h; rem[row] = rm;
    uw[row] = p * st + nh * rm;
  }
}

// ------------------------------------------------------------------
// Per-batch dead detector: block b sets bflag[b]=1 once its 1024 rows
// all have hp >= 1 AND uw == 0. Monotone (never unset).
// ------------------------------------------------------------------
__global__ __launch_bounds__(256)
void k_flag(const float* __restrict__ hp, const float* __restrict__ uw,
            int* __restrict__ bflag)
{
  const int b = blockIdx.x;
  if (bflag[b]) return;
  const int t = threadIdx.x;
  const int base = b * 1024;
  float mn = 1e30f, mxw = 0.0f;
  {
    f32x4 v = *(const f32x4*)(hp + base + t * 4);
    f32x4 u = *(const f32x4*)(uw + base + t * 4);
#pragma unroll
    for (int q = 0; q < 4; q++) { mn = fminf(mn, v[q]); mxw = fmaxf(mxw, u[q]); }
  }
#pragma unroll
  for (int mk = 1; mk < 64; mk <<= 1) {
    mn = fminf(mn, __shfl_xor(mn, mk, 64));
    mxw = fmaxf(mxw, __shfl_xor(mxw, mk, 64));
  }
  __shared__ float part[4], partw[4];
  if ((t & 63) == 0) { part[t >> 6] = mn; partw[t >> 6] = mxw; }
  __syncthreads();
  if (t == 0) {
    mn = fminf(fminf(part[0], part[1]), fminf(part[2], part[3]));
    mxw = fmaxf(fmaxf(partw[0], partw[1]), fmaxf(partw[2], partw[3]));
    if (mn >= 1.0f && mxw == 0.0f) bflag[b] = 1;
  }
}

__global__ void k_zeroflag(int* __restrict__ bflag)
{
  if (threadIdx.x < 8) bflag[threadIdx.x] = 0;
}

// ------------------------------------------------------------------
__global__ void k_pos_ts(float* __restrict__ pos, float* __restrict__ ts,
                         const int* __restrict__ outer)
{
  const int idx = blockIdx.x * 256 + threadIdx.x;
  const int l = idx >> 9, i = idx & 511;
  const float dt = expf((float)(i & ~1) * (-9.210340371976184f / 512.0f));
  const float a = (float)l * dt;
  pos[idx] = (i & 1) ? cosf(a) : sinf(a);
  if (l < 6) {
    const int gidx = 6 * outer[0] + l;
    const float a2 = (float)gidx * dt;
    ts[l * 512 + i] = (i & 1) ? cosf(a2) : sinf(a2);
  }
}

__global__ void k_f2b(const float* __restrict__ in, bf16_t* __restrict__ out, int n)
{
  const int i = blockIdx.x * 256 + threadIdx.x;
  if (i < n) out[i] = (bf16_t)in[i];
}

__global__ void k_copy(const float* __restrict__ in, float* __restrict__ out, int n)
{
  const int i = blockIdx.x * 256 + threadIdx.x;
  if (i < n) out[i] = in[i];
}

// ------------------------------------------------------------------
extern "C" void kernel_launch(void* const* d_in, const int* in_sizes, int n_in,
                              void* d_out, int out_size, void* d_ws, size_t ws_size,
                              hipStream_t stream)
{
  const float* state = (const float*)d_in[0];
  const int*   outer = (const int*)d_in[1];
  const float* p_w   = (const float*)d_in[2];
  const float* p_b   = (const float*)d_in[3];
  const float* wq = (const float*)d_in[4];
  const float* bq = (const float*)d_in[5];
  const float* wk = (const float*)d_in[6];
  const float* bk = (const float*)d_in[7];
  const float* wv = (const float*)d_in[8];
  const float* bv = (const float*)d_in[9];
  const float* wo = (const float*)d_in[10];
  const float* bo = (const float*)d_in[11];
  const float* w1 = (const float*)d_in[12];
  const float* b1 = (const float*)d_in[13];
  const float* w2 = (const float*)d_in[14];
  const float* b2 = (const float*)d_in[15];
  const float* ln1g = (const float*)d_in[16];
  const float* ln1b = (const float*)d_in[17];
  const float* ln2g = (const float*)d_in[18];
  const float* ln2b = (const float*)d_in[19];
  float* prev = (float*)d_out;

  char* cur = (char*)d_ws;
  auto take = [&](size_t n) { char* p = cur; cur += (n + 255) & ~(size_t)255; return p; };
  float*  pos   = (float*) take((size_t)1024 * 512 * 4);
  float*  ts    = (float*) take(6 * 512 * 4);
  bf16_t* wqkvB = (bf16_t*)take((size_t)1536 * 512 * 2);
  bf16_t* woB   = (bf16_t*)take((size_t)512 * 512 * 2);
  bf16_t* w1B   = (bf16_t*)take((size_t)2048 * 512 * 2);
  bf16_t* w2B   = (bf16_t*)take((size_t)512 * 2048 * 2);
  float*  bqkv  = (float*) take(1536 * 4);
  bf16_t* x1B   = (bf16_t*)take((size_t)8192 * 512 * 2);  // LN1 output
  bf16_t* pA    = (bf16_t*)take((size_t)8192 * 512 * 2);  // O-proj half1, then FFN2 half0
  char*   tmp   = take((size_t)8192 * 512 * 2);           // vt, then O-proj half0
  bf16_t* attnO = (bf16_t*)take((size_t)8192 * 512 * 2);  // attn out, then FFN2 half1
  float*  hp    = (float*) take(8192 * 4);
  float*  rem   = (float*) take(8192 * 4);
  float*  uw    = (float*) take(8192 * 4);
  int*    bflag = (int*)   take(8 * 4);
  char*   region = take((size_t)8192 * 2048 * 2);
  bf16_t* xB  = (bf16_t*)region;                            // bf16 state (QKV input + LN1 residual)
  bf16_t* qkv = (bf16_t*)(region + (size_t)8192 * 512 * 2); // Q|K cols live, V garbage
  bf16_t* hB  = (bf16_t*)region;                            // FFN1 out (overwrites xB+qkv)
  bf16_t* vt  = (bf16_t*)tmp;                               // V^T, written by QKV epilogue
  bf16_t* o0  = (bf16_t*)tmp;                               // O-proj split-K half0 (after attn)
  bf16_t* o1  = pA;                                         // O-proj split-K half1
  bf16_t* pB  = attnO;                                      // FFN2 half1 (after O-proj)

  // ---- precompute ----
  k_zeroflag<<<dim3(1), dim3(64), 0, stream>>>(bflag);
  k_pos_ts<<<dim3(2048), dim3(256), 0, stream>>>(pos, ts, outer);
  k_f2b<<<dim3(1024), dim3(256), 0, stream>>>(wq, wqkvB,               512 * 512);
  k_f2b<<<dim3(1024), dim3(256), 0, stream>>>(wk, wqkvB + 512 * 512,   512 * 512);
  k_f2b<<<dim3(1024), dim3(256), 0, stream>>>(wv, wqkvB + 1024 * 512,  512 * 512);
  k_f2b<<<dim3(1024), dim3(256), 0, stream>>>(wo, woB,                 512 * 512);
  k_f2b<<<dim3(4096), dim3(256), 0, stream>>>(w1, w1B,                 2048 * 512);
  k_f2b<<<dim3(4096), dim3(256), 0, stream>>>(w2, w2B,                 512 * 2048);
  k_copy<<<dim3(2), dim3(256), 0, stream>>>(bq, bqkv,        512);
  k_copy<<<dim3(2), dim3(256), 0, stream>>>(bk, bqkv + 512,  512);
  k_copy<<<dim3(2), dim3(256), 0, stream>>>(bv, bqkv + 1024, 512);

  // step 0 top: xB = bf16(state + pos + ts[0]); halting gate
  k_poshalt<<<dim3(8192), dim3(256), 0, stream>>>(state, xB, pos, ts, p_w, p_b, hp, rem, uw);

  // ---- 6 hops ----
  for (int step = 0; step < 6; step++) {
    gemm_bt<false, true ><<<dim3(64, 12), dim3(256), 0, stream>>>(xB, wqkvB, bqkv, qkv, vt, 8192, 1536, 512, bflag);
    k_attn<<<dim3(64, 8), dim3(512), 0, stream>>>(qkv, vt, attnO, bflag);
    // O-proj split-K=2: half0 -> o0 (+bias), half1 -> o1
    gemm_bt512<<<dim3(64, 4, 2), dim3(512), 0, stream>>>(attnO, woB, bo, o0, o1, 8192, 512, 512, 256, bflag);
    k_addln1<<<dim3(8192), dim3(256), 0, stream>>>(xB, o0, o1, ln1g, ln1b, x1B, bflag);
    gemm_bt<true, false><<<dim3(64, 16), dim3(256), 0, stream>>>(x1B, w1B, b1, hB, nullptr, 8192, 2048, 512, bflag);
    // FFN2 split-K=2: half0 -> pA (+bias), half1 -> pB
    gemm_bt512<<<dim3(64, 4, 2), dim3(512), 0, stream>>>(hB, w2B, b2, pA, pB, 8192, 512, 2048, 1024, bflag);
    if (step < 5) {
      k_lnhalt<false><<<dim3(8192), dim3(256), 0, stream>>>(x1B, pA, pB, ln2g, ln2b, pos, ts, step + 1,
                                                            p_w, p_b, xB, hp, rem, uw, prev, step, bflag);
      k_flag<<<dim3(8), dim3(256), 0, stream>>>(hp, uw, bflag);
    } else {
      k_lnhalt<true><<<dim3(8192), dim3(256), 0, stream>>>(x1B, pA, pB, ln2g, ln2b, pos, ts, 0,
                                                           p_w, p_b, xB, hp, rem, uw, prev, step, bflag);
    }
  }
}

// Round 14
// 639.895 us; speedup vs baseline: 1.2643x; 1.2643x over previous
//
#include <hip/hip_runtime.h>
#include <hip/hip_bf16.h>

typedef __bf16 bf16_t;
typedef __bf16 bf16x8 __attribute__((ext_vector_type(8)));
typedef __bf16 bf16x4 __attribute__((ext_vector_type(4)));
typedef __bf16 bf16x2 __attribute__((ext_vector_type(2)));
typedef float  f32x4  __attribute__((ext_vector_type(4)));
typedef float  f32x2  __attribute__((ext_vector_type(2)));
typedef float  f32x8  __attribute__((ext_vector_type(8)));

static __device__ __forceinline__ void gload_lds16(const void* g, void* l) {
  __builtin_amdgcn_global_load_lds((const __attribute__((address_space(1))) void*)g,
                                   (__attribute__((address_space(3))) void*)l, 16, 0, 0);
}

// LDS chunk swizzle for [rows][32] bf16 tiles: chunk' = chunk ^ ((row>>1)&3).
// Per-batch dead flags: bflag[b]==1 once all 1024 positions of batch b have
// halted (hp>=1) AND uw==0 -> that batch's remaining compute is provably
// dead w.r.t. prev (attention never mixes across batches). Bit-exact skip.

// ------------------------------------------------------------------
// GEMM  C = A*B^T (+bias, relu opt), bf16 out. 128x128 tile, BK=32,
// 4 waves, 2-phase dbuf. VT=true (QKV): output tiles with n0>=1024
// are the V columns -> written TRANSPOSED into vt (per (b,h): d x key).
// M-tiles (128 rows) align with batches (1024 rows): batch = bid.x>>3.
// ------------------------------------------------------------------
template <bool RELU, bool VT>
__global__ __launch_bounds__(256)
void gemm_bt(const bf16_t* __restrict__ A, const bf16_t* __restrict__ B,
             const float* __restrict__ bias, bf16_t* __restrict__ C,
             bf16_t* __restrict__ vt, int M, int N, int K,
             const int* __restrict__ bflag)
{
  if (bflag[blockIdx.x >> 3]) return;
  __shared__ bf16_t As[2][128 * 32];
  __shared__ bf16_t Bs[2][128 * 32];
  const int tid = threadIdx.x;
  const int lane = tid & 63, wave = tid >> 6;
  const int wr = (wave >> 1) * 64, wc = (wave & 1) * 64;
  const int lr = lane & 15, lg = lane >> 4;
  const int m0 = blockIdx.x * 128, n0 = blockIdx.y * 128;

  const bf16_t* Ab = A + (size_t)m0 * K;
  const bf16_t* Bb = B + (size_t)n0 * K;

  f32x4 acc[4][4] = {};

  const int r0 = tid >> 2;
  const int c0 = (((tid & 3) ^ ((r0 >> 1) & 3)) * 8);
  const int lsw = (lg ^ ((lr >> 1) & 3)) * 8;

  auto stage = [&](int buf, int kk) {
    gload_lds16(Ab + (size_t)r0 * K + kk + c0,        &As[buf][tid * 8]);
    gload_lds16(Bb + (size_t)r0 * K + kk + c0,        &Bs[buf][tid * 8]);
    gload_lds16(Ab + (size_t)(r0 + 64) * K + kk + c0, &As[buf][(tid + 256) * 8]);
    gload_lds16(Bb + (size_t)(r0 + 64) * K + kk + c0, &Bs[buf][(tid + 256) * 8]);
  };

  stage(0, 0);
  __syncthreads();

  const int nk = K >> 5;
  for (int t = 0; t < nk; ++t) {
    const int buf = t & 1;
    if (t + 1 < nk) stage(buf ^ 1, (t + 1) * 32);
    bf16x8 af[4], bfr[4];
#pragma unroll
    for (int i = 0; i < 4; i++) af[i]  = *(const bf16x8*)(&As[buf][(wr + i * 16 + lr) * 32 + lsw]);
#pragma unroll
    for (int j = 0; j < 4; j++) bfr[j] = *(const bf16x8*)(&Bs[buf][(wc + j * 16 + lr) * 32 + lsw]);
#pragma unroll
    for (int i = 0; i < 4; i++)
#pragma unroll
      for (int j = 0; j < 4; j++)
        acc[i][j] = __builtin_amdgcn_mfma_f32_16x16x32_bf16(af[i], bfr[j], acc[i][j], 0, 0, 0);
    __syncthreads();
  }

  const int rg = (lane >> 4) * 4;
  if (VT && n0 >= 1024) {
#pragma unroll
    for (int j = 0; j < 4; j++) {
      const int col = n0 + wc + j * 16 + lr;      // 1024..1535
      const float bv = bias[col];
      const int hd = col - 1024;                  // h*64 + d
#pragma unroll
      for (int i = 0; i < 4; i++) {
        const int row0 = m0 + wr + i * 16 + rg;   // token index
        const int bb = row0 >> 10, key = row0 & 1023;
        bf16x4 q;
#pragma unroll
        for (int r = 0; r < 4; r++) q[r] = (bf16_t)(acc[i][j][r] + bv);
        *(bf16x4*)(vt + ((size_t)bb * 512 + hd) * 1024 + key) = q;
      }
    }
  } else {
#pragma unroll
    for (int j = 0; j < 4; j++) {
      const int col = n0 + wc + j * 16 + lr;
      const float bv = bias ? bias[col] : 0.0f;
#pragma unroll
      for (int i = 0; i < 4; i++) {
#pragma unroll
        for (int r = 0; r < 4; r++) {
          const int row = m0 + wr + i * 16 + rg + r;
          float v = acc[i][j][r] + bv;
          if (RELU) v = fmaxf(v, 0.0f);
          C[(size_t)row * N + col] = (bf16_t)v;
        }
      }
    }
  }
}

// ------------------------------------------------------------------
// GEMM 128x128, 512 threads / 8 waves (2x4), wave = 64x32, 2-phase
// dbuf, bf16 output, split-K via gridDim.z (z-half k writes buffer
// Ck; bias folded into half 0 only). O-proj (z=2), FFN2 (z=2).
// ------------------------------------------------------------------
__global__ __launch_bounds__(512)
void gemm_bt512(const bf16_t* __restrict__ A, const bf16_t* __restrict__ B,
                const float* __restrict__ bias, bf16_t* __restrict__ C0,
                bf16_t* __restrict__ C1, int M, int N, int Kfull, int Keff,
                const int* __restrict__ bflag)
{
  if (bflag[blockIdx.x >> 3]) return;
  __shared__ bf16_t As[2][128 * 32];
  __shared__ bf16_t Bs[2][128 * 32];
  const int tid = threadIdx.x;
  const int lane = tid & 63, wave = tid >> 6;
  const int wr = (wave >> 2) * 64, wc = (wave & 3) * 32;
  const int lr = lane & 15, lg = lane >> 4;
  const int m0 = blockIdx.x * 128, n0 = blockIdx.y * 128;
  const int kb = blockIdx.z;

  const bf16_t* Ab = A + (size_t)m0 * Kfull + (size_t)kb * Keff;
  const bf16_t* Bb = B + (size_t)n0 * Kfull + (size_t)kb * Keff;
  bf16_t* C = kb ? C1 : C0;

  f32x4 acc[4][2] = {};

  const int r0 = tid >> 2;
  const int c0 = (((tid & 3) ^ ((r0 >> 1) & 3)) * 8);
  const int lsw = (lg ^ ((lr >> 1) & 3)) * 8;

  auto stage = [&](int buf, int kk) {
    gload_lds16(Ab + (size_t)r0 * Kfull + kk + c0, &As[buf][tid * 8]);
    gload_lds16(Bb + (size_t)r0 * Kfull + kk + c0, &Bs[buf][tid * 8]);
  };

  stage(0, 0);
  __syncthreads();

  const int nk = Keff >> 5;
  for (int t = 0; t < nk; ++t) {
    const int buf = t & 1;
    if (t + 1 < nk) stage(buf ^ 1, (t + 1) * 32);
    bf16x8 af[4], bfr[2];
#pragma unroll
    for (int i = 0; i < 4; i++) af[i]  = *(const bf16x8*)(&As[buf][(wr + i * 16 + lr) * 32 + lsw]);
#pragma unroll
    for (int j = 0; j < 2; j++) bfr[j] = *(const bf16x8*)(&Bs[buf][(wc + j * 16 + lr) * 32 + lsw]);
#pragma unroll
    for (int i = 0; i < 4; i++)
#pragma unroll
      for (int j = 0; j < 2; j++)
        acc[i][j] = __builtin_amdgcn_mfma_f32_16x16x32_bf16(af[i], bfr[j], acc[i][j], 0, 0, 0);
    __syncthreads();
  }

  const int rg = (lane >> 4) * 4;
#pragma unroll
  for (int j = 0; j < 2; j++) {
    const int col = n0 + wc + j * 16 + lr;
    const float bv = (bias && kb == 0) ? bias[col] : 0.0f;
#pragma unroll
    for (int i = 0; i < 4; i++) {
#pragma unroll
      for (int r = 0; r < 4; r++) {
        const int row = m0 + wr + i * 16 + rg + r;
        C[(size_t)row * N + col] = (bf16_t)(acc[i][j][r] + bv);
      }
    }
  }
}

// ------------------------------------------------------------------
// Flash attention (swapped QK^T): S^T = mfma(K,Q), per-lane scalar
// online softmax with defer-max, cvt_pk P-packing, K/V^T LDS dbuf
// with XOR swizzle, setprio around MFMA.  (Round-12 proven version:
// V must stay LDS-staged — direct L2 reads serialize, +100% dur.)
// ------------------------------------------------------------------
__global__ __launch_bounds__(512)
void k_attn(const bf16_t* __restrict__ qkv, const bf16_t* __restrict__ vt,
            bf16_t* __restrict__ out, const int* __restrict__ bflag)
{
  if (bflag[blockIdx.x >> 3]) return;
  const int bh = blockIdx.x;
  const int qt = blockIdx.y;
  const int b = bh >> 3, h = bh & 7;
  const int tid = threadIdx.x, lane = tid & 63, wave = tid >> 6;
  const int lr = lane & 15, lg = lane >> 4;

  __shared__ bf16_t Ks[2][4096];
  __shared__ bf16_t Vs[2][4096];
  __shared__ bf16_t Pl[8][16][68];

  const size_t RS = 1536;
  const bf16_t* Qb = qkv + ((size_t)(b * 1024 + qt * 128)) * RS + h * 64;
  const bf16_t* Kb = qkv + ((size_t)(b * 1024)) * RS + 512 + h * 64;
  const bf16_t* Vt = vt + (size_t)bh * 64 * 1024;

  const float SC = 0.125f * 1.4426950408889634f;
  bf16x8 qf[2];
#pragma unroll
  for (int ks = 0; ks < 2; ks++) {
    bf16x8 q = *(const bf16x8*)(Qb + (size_t)(wave * 16 + lr) * RS + lg * 8 + ks * 32);
#pragma unroll
    for (int u = 0; u < 8; u++) q[u] = (bf16_t)((float)q[u] * SC);
    qf[ks] = q;
  }

  f32x4 o[4] = {};
  float m_ = -1e30f, ls_ = 0.0f;     // per-lane: q-row = wave*16 + lane&15

  auto stage = [&](int buf, int kv) {
    const int c = tid;
    const int r = c >> 3;
    const int ce = (c & 7) * 8;
    const int cs = ce ^ ((r & 7) << 3);
    gload_lds16(Kb + (size_t)(kv * 64 + r) * RS + cs, &Ks[buf][c * 8]);
    gload_lds16(Vt + (size_t)r * 1024 + kv * 64 + cs, &Vs[buf][c * 8]);
  };

  stage(0, 0);
  __syncthreads();

  const int sw = (lr & 7) << 3;

  for (int kv = 0; kv < 16; kv++) {
    const int buf = kv & 1;
    if (kv < 15) stage(buf ^ 1, kv + 1);

    f32x4 sfr[4];
    __builtin_amdgcn_s_setprio(1);
#pragma unroll
    for (int j = 0; j < 4; j++) {
      f32x4 z = {};
#pragma unroll
      for (int ks = 0; ks < 2; ks++) {
        bf16x8 kf = *(const bf16x8*)(&Ks[buf][(j * 16 + lr) * 64 + ((lg * 8 + ks * 32) ^ sw)]);
        z = __builtin_amdgcn_mfma_f32_16x16x32_bf16(kf, qf[ks], z, 0, 0, 0);
      }
      sfr[j] = z;
    }
    __builtin_amdgcn_s_setprio(0);

    float px = sfr[0][0];
#pragma unroll
    for (int j = 0; j < 4; j++)
#pragma unroll
      for (int r = 0; r < 4; r++) px = fmaxf(px, sfr[j][r]);
    if (!__all(px <= m_ + 8.0f)) {
      float mx = fmaxf(px, __shfl_xor(px, 16, 64));
      mx = fmaxf(mx, __shfl_xor(mx, 32, 64));
      mx = fmaxf(mx, m_);
      const float al = __builtin_amdgcn_exp2f(m_ - mx);
      m_ = mx;
      ls_ *= al;
      float aq[4];
#pragma unroll
      for (int r = 0; r < 4; r++) aq[r] = __shfl(al, lg * 4 + r, 64);
#pragma unroll
      for (int j = 0; j < 4; j++)
#pragma unroll
        for (int r = 0; r < 4; r++) o[j][r] *= aq[r];
    }

    float ps = 0.0f;
#pragma unroll
    for (int j = 0; j < 4; j++) {
      const float p0 = __builtin_amdgcn_exp2f(sfr[j][0] - m_);
      const float p1 = __builtin_amdgcn_exp2f(sfr[j][1] - m_);
      const float p2 = __builtin_amdgcn_exp2f(sfr[j][2] - m_);
      const float p3 = __builtin_amdgcn_exp2f(sfr[j][3] - m_);
      ps += (p0 + p1) + (p2 + p3);
      unsigned lo, hi;
      asm("v_cvt_pk_bf16_f32 %0, %1, %2" : "=v"(lo) : "v"(p0), "v"(p1));
      asm("v_cvt_pk_bf16_f32 %0, %1, %2" : "=v"(hi) : "v"(p2), "v"(p3));
      uint2 w; w.x = lo; w.y = hi;
      *(uint2*)(&Pl[wave][lr][j * 16 + lg * 4]) = w;
    }
    ls_ += ps;

    __builtin_amdgcn_s_setprio(1);
#pragma unroll
    for (int ks = 0; ks < 2; ks++) {
      bf16x8 pa = *(const bf16x8*)(&Pl[wave][lr][lg * 8 + ks * 32]);
#pragma unroll
      for (int j = 0; j < 4; j++) {
        bf16x8 vb = *(const bf16x8*)(&Vs[buf][(j * 16 + lr) * 64 + ((lg * 8 + ks * 32) ^ sw)]);
        o[j] = __builtin_amdgcn_mfma_f32_16x16x32_bf16(pa, vb, o[j], 0, 0, 0);
      }
    }
    __builtin_amdgcn_s_setprio(0);

    __syncthreads();
  }

  ls_ += __shfl_xor(ls_, 16, 64);
  ls_ += __shfl_xor(ls_, 32, 64);
  float lsq[4];
#pragma unroll
  for (int r = 0; r < 4; r++) lsq[r] = __shfl(ls_, lg * 4 + r, 64);

  const size_t orow = (size_t)(b * 1024 + qt * 128 + wave * 16 + lg * 4);
#pragma unroll
  for (int j = 0; j < 4; j++)
#pragma unroll
    for (int r = 0; r < 4; r++)
      out[(orow + r) * 512 + h * 64 + j * 16 + lr] = (bf16_t)(o[j][r] / lsq[r]);
}

// ------------------------------------------------------------------
// Step 0 top: x = state + pos + ts[0] (bf16 out only — xB doubles as
// the LN1 residual); p = sigmoid(x . p_w + p_b); ACT halting update.
// ------------------------------------------------------------------
__global__ __launch_bounds__(256)
void k_poshalt(const float* __restrict__ state, bf16_t* __restrict__ xbf,
               const float* __restrict__ pos, const float* __restrict__ ts,
               const float* __restrict__ pw, const float* __restrict__ pb,
               float* __restrict__ hp, float* __restrict__ rem, float* __restrict__ uw)
{
  const int row = blockIdx.x;
  const int l = row & 1023;
  const int t = threadIdx.x;
  const size_t base = (size_t)row * 512;
  float v0 = state[base + t]       + pos[l * 512 + t]       + ts[t];
  float v1 = state[base + 256 + t] + pos[l * 512 + 256 + t] + ts[256 + t];
  xbf[base + t] = (bf16_t)v0; xbf[base + 256 + t] = (bf16_t)v1;

  float d = v0 * pw[t] + v1 * pw[256 + t];
#pragma unroll
  for (int mk = 1; mk < 64; mk <<= 1) d += __shfl_xor(d, mk, 64);
  __shared__ float part[4];
  if ((t & 63) == 0) part[t >> 6] = d;
  __syncthreads();
  if (t == 0) {
    const float z = part[0] + part[1] + part[2] + part[3] + pb[0];
    const float p = 1.0f / (1.0f + expf(-z));
    float h = 0.0f, rm = 0.0f;
    const float cond = p;
    const float nh = (cond > 0.9f) ? 1.0f : 0.0f;
    const float st = (cond <= 0.9f) ? 1.0f : 0.0f;
    h += p * st;
    rm += nh * (1.0f - h);
    h += nh * rm;
    hp[row] = h; rem[row] = rm;
    uw[row] = p * st + nh * rm;
  }
}

// ------------------------------------------------------------------
// Post-attn LN: y = LayerNorm(xB + o0 + o1)  (all bf16; o0/o1 are the
// O-proj split-K halves); write y bf16 only.
// ------------------------------------------------------------------
__global__ __launch_bounds__(256)
void k_addln1(const bf16_t* __restrict__ xb, const bf16_t* __restrict__ o0,
              const bf16_t* __restrict__ o1,
              const float* __restrict__ g, const float* __restrict__ be,
              bf16_t* __restrict__ ybf, const int* __restrict__ bflag)
{
  if (bflag[blockIdx.x >> 10]) return;
  const int row = blockIdx.x, t = threadIdx.x;
  const size_t base = (size_t)row * 512 + 2 * t;
  bf16x2 xv = *(const bf16x2*)(xb + base);
  bf16x2 a0 = *(const bf16x2*)(o0 + base);
  bf16x2 a1 = *(const bf16x2*)(o1 + base);
  const float v0 = (float)xv[0] + (float)a0[0] + (float)a1[0];
  const float v1 = (float)xv[1] + (float)a0[1] + (float)a1[1];
  float s1 = v0 + v1, s2 = v0 * v0 + v1 * v1;
#pragma unroll
  for (int mk = 1; mk < 64; mk <<= 1) { s1 += __shfl_xor(s1, mk, 64); s2 += __shfl_xor(s2, mk, 64); }
  __shared__ float p1[4], p2[4];
  if ((t & 63) == 0) { p1[t >> 6] = s1; p2[t >> 6] = s2; }
  __syncthreads();
  s1 = p1[0] + p1[1] + p1[2] + p1[3];
  s2 = p2[0] + p2[1] + p2[2] + p2[3];
  const float mean = s1 * (1.0f / 512.0f);
  const float var  = s2 * (1.0f / 512.0f) - mean * mean;
  const float ri = rsqrtf(var + 1e-5f);
  f32x2 gv = *(const f32x2*)(g + 2 * t);
  f32x2 bv = *(const f32x2*)(be + 2 * t);
  bf16x2 yo;
  yo[0] = (bf16_t)((v0 - mean) * ri * gv[0] + bv[0]);
  yo[1] = (bf16_t)((v1 - mean) * ri * gv[1] + bv[1]);
  *(bf16x2*)(ybf + base) = yo;
}

// ------------------------------------------------------------------
// Fused bottom-of-step: y = LN(x1B + pA + pB) (bf16 inputs);
// prev = y*uw + prev*(1-uw); then NEXT step's pos/ts add + halting
// (writes only xB, the bf16 state that doubles as next residual).
// ------------------------------------------------------------------
template <bool LAST>
__global__ __launch_bounds__(256)
void k_lnhalt(const bf16_t* __restrict__ x1b, const bf16_t* __restrict__ pA,
              const bf16_t* __restrict__ pB,
              const float* __restrict__ g, const float* __restrict__ be,
              const float* __restrict__ pos, const float* __restrict__ ts, int nstep,
              const float* __restrict__ pw, const float* __restrict__ pb,
              bf16_t* __restrict__ xbf,
              float* __restrict__ hp, float* __restrict__ rem, float* __restrict__ uw,
              float* __restrict__ prev, int step, const int* __restrict__ bflag)
{
  if (bflag[blockIdx.x >> 10]) return;
  const int row = blockIdx.x, t = threadIdx.x;
  const int l = row & 1023;
  const size_t base = (size_t)row * 512 + 2 * t;
  bf16x2 xv = *(const bf16x2*)(x1b + base);
  bf16x2 av = *(const bf16x2*)(pA + base);
  bf16x2 bv2 = *(const bf16x2*)(pB + base);
  const float a0 = (float)xv[0] + (float)av[0] + (float)bv2[0];
  const float a1 = (float)xv[1] + (float)av[1] + (float)bv2[1];
  float s1 = a0 + a1, s2 = a0 * a0 + a1 * a1;
#pragma unroll
  for (int mk = 1; mk < 64; mk <<= 1) { s1 += __shfl_xor(s1, mk, 64); s2 += __shfl_xor(s2, mk, 64); }
  __shared__ float p1[4], p2[4], pd[4];
  if ((t & 63) == 0) { p1[t >> 6] = s1; p2[t >> 6] = s2; }
  __syncthreads();
  s1 = p1[0] + p1[1] + p1[2] + p1[3];
  s2 = p2[0] + p2[1] + p2[2] + p2[3];
  const float mean = s1 * (1.0f / 512.0f);
  const float var  = s2 * (1.0f / 512.0f) - mean * mean;
  const float ri = rsqrtf(var + 1e-5f);
  f32x2 gv = *(const f32x2*)(g + 2 * t);
  f32x2 bev = *(const f32x2*)(be + 2 * t);
  const float y0 = (a0 - mean) * ri * gv[0] + bev[0];
  const float y1 = (a1 - mean) * ri * gv[1] + bev[1];

  const float w = uw[row];
  if (step == 0) {
    f32x2 np; np[0] = y0 * w; np[1] = y1 * w;
    *(f32x2*)(prev + base) = np;
  } else if (w != 0.0f) {
    f32x2 pv = *(const f32x2*)(prev + base);
    f32x2 np;
    np[0] = y0 * w + pv[0] * (1.0f - w);
    np[1] = y1 * w + pv[1] * (1.0f - w);
    *(f32x2*)(prev + base) = np;
  }

  if (LAST) return;

  f32x2 pp = *(const f32x2*)(pos + l * 512 + 2 * t);
  f32x2 tv = *(const f32x2*)(ts + nstep * 512 + 2 * t);
  const float v0 = y0 + pp[0] + tv[0];
  const float v1 = y1 + pp[1] + tv[1];
  bf16x2 xo; xo[0] = (bf16_t)v0; xo[1] = (bf16_t)v1;
  *(bf16x2*)(xbf + base) = xo;

  f32x2 wv = *(const f32x2*)(pw + 2 * t);
  float d = v0 * wv[0] + v1 * wv[1];
#pragma unroll
  for (int mk = 1; mk < 64; mk <<= 1) d += __shfl_xor(d, mk, 64);
  if ((t & 63) == 0) pd[t >> 6] = d;
  __syncthreads();
  if (t == 0) {
    const float z = pd[0] + pd[1] + pd[2] + pd[3] + pb[0];
    const float p = 1.0f / (1.0f + expf(-z));
    float h  = hp[row];
    float rm = rem[row];
    const float still0 = (h < 1.0f) ? 1.0f : 0.0f;
    const float cond = h + p * still0;
    const float nh = (cond > 0.9f) ? still0 : 0.0f;
    const float st = (cond <= 0.9f) ? still0 : 0.0f;
    h += p * st;
    rm += nh * (1.0f - h);
    h += nh * rm;
    hp[row] = h; rem[row] = rm;
    uw[row] = p * st + nh * rm;
  }
}

// ------------------------------------------------------------------
// Per-batch dead detector: block b sets bflag[b]=1 once its 1024 rows
// all have hp >= 1 AND uw == 0. Monotone (never unset).
// ------------------------------------------------------------------
__global__ __launch_bounds__(256)
void k_flag(const float* __restrict__ hp, const float* __restrict__ uw,
            int* __restrict__ bflag)
{
  const int b = blockIdx.x;
  if (bflag[b]) return;
  const int t = threadIdx.x;
  const int base = b * 1024;
  float mn = 1e30f, mxw = 0.0f;
  {
    f32x4 v = *(const f32x4*)(hp + base + t * 4);
    f32x4 u = *(const f32x4*)(uw + base + t * 4);
#pragma unroll
    for (int q = 0; q < 4; q++) { mn = fminf(mn, v[q]); mxw = fmaxf(mxw, u[q]); }
  }
#pragma unroll
  for (int mk = 1; mk < 64; mk <<= 1) {
    mn = fminf(mn, __shfl_xor(mn, mk, 64));
    mxw = fmaxf(mxw, __shfl_xor(mxw, mk, 64));
  }
  __shared__ float part[4], partw[4];
  if ((t & 63) == 0) { part[t >> 6] = mn; partw[t >> 6] = mxw; }
  __syncthreads();
  if (t == 0) {
    mn = fminf(fminf(part[0], part[1]), fminf(part[2], part[3]));
    mxw = fmaxf(fmaxf(partw[0], partw[1]), fmaxf(partw[2], partw[3]));
    if (mn >= 1.0f && mxw == 0.0f) bflag[b] = 1;
  }
}

__global__ void k_zeroflag(int* __restrict__ bflag)
{
  if (threadIdx.x < 8) bflag[threadIdx.x] = 0;
}

// ------------------------------------------------------------------
__global__ void k_pos_ts(float* __restrict__ pos, float* __restrict__ ts,
                         const int* __restrict__ outer)
{
  const int idx = blockIdx.x * 256 + threadIdx.x;
  const int l = idx >> 9, i = idx & 511;
  const float dt = expf((float)(i & ~1) * (-9.210340371976184f / 512.0f));
  const float a = (float)l * dt;
  pos[idx] = (i & 1) ? cosf(a) : sinf(a);
  if (l < 6) {
    const int gidx = 6 * outer[0] + l;
    const float a2 = (float)gidx * dt;
    ts[l * 512 + i] = (i & 1) ? cosf(a2) : sinf(a2);
  }
}

__global__ void k_f2b(const float* __restrict__ in, bf16_t* __restrict__ out, int n)
{
  const int i = blockIdx.x * 256 + threadIdx.x;
  if (i < n) out[i] = (bf16_t)in[i];
}

__global__ void k_copy(const float* __restrict__ in, float* __restrict__ out, int n)
{
  const int i = blockIdx.x * 256 + threadIdx.x;
  if (i < n) out[i] = in[i];
}

// ------------------------------------------------------------------
extern "C" void kernel_launch(void* const* d_in, const int* in_sizes, int n_in,
                              void* d_out, int out_size, void* d_ws, size_t ws_size,
                              hipStream_t stream)
{
  const float* state = (const float*)d_in[0];
  const int*   outer = (const int*)d_in[1];
  const float* p_w   = (const float*)d_in[2];
  const float* p_b   = (const float*)d_in[3];
  const float* wq = (const float*)d_in[4];
  const float* bq = (const float*)d_in[5];
  const float* wk = (const float*)d_in[6];
  const float* bk = (const float*)d_in[7];
  const float* wv = (const float*)d_in[8];
  const float* bv = (const float*)d_in[9];
  const float* wo = (const float*)d_in[10];
  const float* bo = (const float*)d_in[11];
  const float* w1 = (const float*)d_in[12];
  const float* b1 = (const float*)d_in[13];
  const float* w2 = (const float*)d_in[14];
  const float* b2 = (const float*)d_in[15];
  const float* ln1g = (const float*)d_in[16];
  const float* ln1b = (const float*)d_in[17];
  const float* ln2g = (const float*)d_in[18];
  const float* ln2b = (const float*)d_in[19];
  float* prev = (float*)d_out;

  char* cur = (char*)d_ws;
  auto take = [&](size_t n) { char* p = cur; cur += (n + 255) & ~(size_t)255; return p; };
  float*  pos   = (float*) take((size_t)1024 * 512 * 4);
  float*  ts    = (float*) take(6 * 512 * 4);
  bf16_t* wqkvB = (bf16_t*)take((size_t)1536 * 512 * 2);
  bf16_t* woB   = (bf16_t*)take((size_t)512 * 512 * 2);
  bf16_t* w1B   = (bf16_t*)take((size_t)2048 * 512 * 2);
  bf16_t* w2B   = (bf16_t*)take((size_t)512 * 2048 * 2);
  float*  bqkv  = (float*) take(1536 * 4);
  bf16_t* x1B   = (bf16_t*)take((size_t)8192 * 512 * 2);  // LN1 output
  bf16_t* pA    = (bf16_t*)take((size_t)8192 * 512 * 2);  // O-proj half1, then FFN2 half0
  char*   tmp   = take((size_t)8192 * 512 * 2);           // vt, then O-proj half0
  bf16_t* attnO = (bf16_t*)take((size_t)8192 * 512 * 2);  // attn out, then FFN2 half1
  float*  hp    = (float*) take(8192 * 4);
  float*  rem   = (float*) take(8192 * 4);
  float*  uw    = (float*) take(8192 * 4);
  int*    bflag = (int*)   take(8 * 4);
  char*   region = take((size_t)8192 * 2048 * 2);
  bf16_t* xB  = (bf16_t*)region;                            // bf16 state (QKV input + LN1 residual)
  bf16_t* qkv = (bf16_t*)(region + (size_t)8192 * 512 * 2); // Q|K cols live, V garbage
  bf16_t* hB  = (bf16_t*)region;                            // FFN1 out (overwrites xB+qkv)
  bf16_t* vt  = (bf16_t*)tmp;                               // V^T, written by QKV epilogue
  bf16_t* o0  = (bf16_t*)tmp;                               // O-proj split-K half0 (after attn)
  bf16_t* o1  = pA;                                         // O-proj split-K half1
  bf16_t* pB  = attnO;                                      // FFN2 half1 (after O-proj)

  // ---- precompute ----
  k_zeroflag<<<dim3(1), dim3(64), 0, stream>>>(bflag);
  k_pos_ts<<<dim3(2048), dim3(256), 0, stream>>>(pos, ts, outer);
  k_f2b<<<dim3(1024), dim3(256), 0, stream>>>(wq, wqkvB,               512 * 512);
  k_f2b<<<dim3(1024), dim3(256), 0, stream>>>(wk, wqkvB + 512 * 512,   512 * 512);
  k_f2b<<<dim3(1024), dim3(256), 0, stream>>>(wv, wqkvB + 1024 * 512,  512 * 512);
  k_f2b<<<dim3(1024), dim3(256), 0, stream>>>(wo, woB,                 512 * 512);
  k_f2b<<<dim3(4096), dim3(256), 0, stream>>>(w1, w1B,                 2048 * 512);
  k_f2b<<<dim3(4096), dim3(256), 0, stream>>>(w2, w2B,                 512 * 2048);
  k_copy<<<dim3(2), dim3(256), 0, stream>>>(bq, bqkv,        512);
  k_copy<<<dim3(2), dim3(256), 0, stream>>>(bk, bqkv + 512,  512);
  k_copy<<<dim3(2), dim3(256), 0, stream>>>(bv, bqkv + 1024, 512);

  // step 0 top: xB = bf16(state + pos + ts[0]); halting gate
  k_poshalt<<<dim3(8192), dim3(256), 0, stream>>>(state, xB, pos, ts, p_w, p_b, hp, rem, uw);

  // ---- 6 hops ----
  for (int step = 0; step < 6; step++) {
    gemm_bt<false, true ><<<dim3(64, 12), dim3(256), 0, stream>>>(xB, wqkvB, bqkv, qkv, vt, 8192, 1536, 512, bflag);
    k_attn<<<dim3(64, 8), dim3(512), 0, stream>>>(qkv, vt, attnO, bflag);
    // O-proj split-K=2: half0 -> o0 (+bias), half1 -> o1
    gemm_bt512<<<dim3(64, 4, 2), dim3(512), 0, stream>>>(attnO, woB, bo, o0, o1, 8192, 512, 512, 256, bflag);
    k_addln1<<<dim3(8192), dim3(256), 0, stream>>>(xB, o0, o1, ln1g, ln1b, x1B, bflag);
    gemm_bt<true, false><<<dim3(64, 16), dim3(256), 0, stream>>>(x1B, w1B, b1, hB, nullptr, 8192, 2048, 512, bflag);
    // FFN2 split-K=2: half0 -> pA (+bias), half1 -> pB
    gemm_bt512<<<dim3(64, 4, 2), dim3(512), 0, stream>>>(hB, w2B, b2, pA, pB, 8192, 512, 2048, 1024, bflag);
    if (step < 5) {
      k_lnhalt<false><<<dim3(8192), dim3(256), 0, stream>>>(x1B, pA, pB, ln2g, ln2b, pos, ts, step + 1,
                                                            p_w, p_b, xB, hp, rem, uw, prev, step, bflag);
      k_flag<<<dim3(8), dim3(256), 0, stream>>>(hp, uw, bflag);
    } else {
      k_lnhalt<true><<<dim3(8192), dim3(256), 0, stream>>>(x1B, pA, pB, ln2g, ln2b, pos, ts, 0,
                                                           p_w, p_b, xB, hp, rem, uw, prev, step, bflag);
    }
  }
}

// Round 15
// 624.661 us; speedup vs baseline: 1.2952x; 1.0244x over previous
//
#include <hip/hip_runtime.h>
#include <hip/hip_bf16.h>

typedef __bf16 bf16_t;
typedef __bf16 bf16x8 __attribute__((ext_vector_type(8)));
typedef __bf16 bf16x4 __attribute__((ext_vector_type(4)));
typedef __bf16 bf16x2 __attribute__((ext_vector_type(2)));
typedef float  f32x4  __attribute__((ext_vector_type(4)));
typedef float  f32x2  __attribute__((ext_vector_type(2)));
typedef float  f32x8  __attribute__((ext_vector_type(8)));

static __device__ __forceinline__ void gload_lds16(const void* g, void* l) {
  __builtin_amdgcn_global_load_lds((const __attribute__((address_space(1))) void*)g,
                                   (__attribute__((address_space(3))) void*)l, 16, 0, 0);
}

// LDS chunk swizzles (rule #21: linear gload_lds dest + inverse-swizzled
// global source + swizzled ds_read):
//   [rows][32] bf16 tiles (64B rows):  chunk' = chunk ^ ((row>>1)&3)
//   [rows][64] bf16 tiles (128B rows): chunk' = chunk ^ (row&7)
// Per-batch dead flags: bflag[b]==1 once all 1024 positions of batch b have
// halted (hp>=1) AND uw==0 -> that batch's remaining compute is provably
// dead w.r.t. prev (attention never mixes across batches). Bit-exact skip.

// ------------------------------------------------------------------
// GEMM  C = A*B^T (+bias, relu opt), bf16 out. 128x128 tile, BK=32,
// 4 waves, 2-phase dbuf. VT=true (QKV): output tiles with n0>=1024
// are the V columns -> written TRANSPOSED into vt (per (b,h): d x key).
// M-tiles (128 rows) align with batches (1024 rows): batch = bid.x>>3.
// ------------------------------------------------------------------
template <bool RELU, bool VT>
__global__ __launch_bounds__(256)
void gemm_bt(const bf16_t* __restrict__ A, const bf16_t* __restrict__ B,
             const float* __restrict__ bias, bf16_t* __restrict__ C,
             bf16_t* __restrict__ vt, int M, int N, int K,
             const int* __restrict__ bflag)
{
  if (bflag[blockIdx.x >> 3]) return;
  __shared__ bf16_t As[2][128 * 32];
  __shared__ bf16_t Bs[2][128 * 32];
  const int tid = threadIdx.x;
  const int lane = tid & 63, wave = tid >> 6;
  const int wr = (wave >> 1) * 64, wc = (wave & 1) * 64;
  const int lr = lane & 15, lg = lane >> 4;
  const int m0 = blockIdx.x * 128, n0 = blockIdx.y * 128;

  const bf16_t* Ab = A + (size_t)m0 * K;
  const bf16_t* Bb = B + (size_t)n0 * K;

  f32x4 acc[4][4] = {};

  const int r0 = tid >> 2;
  const int c0 = (((tid & 3) ^ ((r0 >> 1) & 3)) * 8);
  const int lsw = (lg ^ ((lr >> 1) & 3)) * 8;

  auto stage = [&](int buf, int kk) {
    gload_lds16(Ab + (size_t)r0 * K + kk + c0,        &As[buf][tid * 8]);
    gload_lds16(Bb + (size_t)r0 * K + kk + c0,        &Bs[buf][tid * 8]);
    gload_lds16(Ab + (size_t)(r0 + 64) * K + kk + c0, &As[buf][(tid + 256) * 8]);
    gload_lds16(Bb + (size_t)(r0 + 64) * K + kk + c0, &Bs[buf][(tid + 256) * 8]);
  };

  stage(0, 0);
  __syncthreads();

  const int nk = K >> 5;
  for (int t = 0; t < nk; ++t) {
    const int buf = t & 1;
    if (t + 1 < nk) stage(buf ^ 1, (t + 1) * 32);
    bf16x8 af[4], bfr[4];
#pragma unroll
    for (int i = 0; i < 4; i++) af[i]  = *(const bf16x8*)(&As[buf][(wr + i * 16 + lr) * 32 + lsw]);
#pragma unroll
    for (int j = 0; j < 4; j++) bfr[j] = *(const bf16x8*)(&Bs[buf][(wc + j * 16 + lr) * 32 + lsw]);
#pragma unroll
    for (int i = 0; i < 4; i++)
#pragma unroll
      for (int j = 0; j < 4; j++)
        acc[i][j] = __builtin_amdgcn_mfma_f32_16x16x32_bf16(af[i], bfr[j], acc[i][j], 0, 0, 0);
    __syncthreads();
  }

  const int rg = (lane >> 4) * 4;
  if (VT && n0 >= 1024) {
#pragma unroll
    for (int j = 0; j < 4; j++) {
      const int col = n0 + wc + j * 16 + lr;      // 1024..1535
      const float bv = bias[col];
      const int hd = col - 1024;                  // h*64 + d
#pragma unroll
      for (int i = 0; i < 4; i++) {
        const int row0 = m0 + wr + i * 16 + rg;   // token index
        const int bb = row0 >> 10, key = row0 & 1023;
        bf16x4 q;
#pragma unroll
        for (int r = 0; r < 4; r++) q[r] = (bf16_t)(acc[i][j][r] + bv);
        *(bf16x4*)(vt + ((size_t)bb * 512 + hd) * 1024 + key) = q;
      }
    }
  } else {
#pragma unroll
    for (int j = 0; j < 4; j++) {
      const int col = n0 + wc + j * 16 + lr;
      const float bv = bias ? bias[col] : 0.0f;
#pragma unroll
      for (int i = 0; i < 4; i++) {
#pragma unroll
        for (int r = 0; r < 4; r++) {
          const int row = m0 + wr + i * 16 + rg + r;
          float v = acc[i][j][r] + bv;
          if (RELU) v = fmaxf(v, 0.0f);
          C[(size_t)row * N + col] = (bf16_t)v;
        }
      }
    }
  }
}

// ------------------------------------------------------------------
// GEMM 128x128, 512 threads / 8 waves (2x4), wave = 64x32, BK=64
// (half the barriers of BK=32 — the per-K-step stage+drain stall is
// ~constant, so 2x compute per stall), 2-phase dbuf (64KB LDS -> 2
// blocks/CU, unchanged), bf16 out, split-K via gridDim.z. Keff must
// be a multiple of 64. O-proj (z=2, Keff=256), FFN2 (z=2, Keff=1024).
// ------------------------------------------------------------------
__global__ __launch_bounds__(512)
void gemm_bt512(const bf16_t* __restrict__ A, const bf16_t* __restrict__ B,
                const float* __restrict__ bias, bf16_t* __restrict__ C0,
                bf16_t* __restrict__ C1, int M, int N, int Kfull, int Keff,
                const int* __restrict__ bflag)
{
  if (bflag[blockIdx.x >> 3]) return;
  __shared__ bf16_t As[2][128 * 64];
  __shared__ bf16_t Bs[2][128 * 64];
  const int tid = threadIdx.x;
  const int lane = tid & 63, wave = tid >> 6;
  const int wr = (wave >> 2) * 64, wc = (wave & 3) * 32;
  const int lr = lane & 15, lg = lane >> 4;
  const int m0 = blockIdx.x * 128, n0 = blockIdx.y * 128;
  const int kb = blockIdx.z;

  const bf16_t* Ab = A + (size_t)m0 * Kfull + (size_t)kb * Keff;
  const bf16_t* Bb = B + (size_t)n0 * Kfull + (size_t)kb * Keff;
  bf16_t* C = kb ? C1 : C0;

  f32x4 acc[4][2] = {};

  // staging: rows of 64 cols = 8 chunks of 8 elems; thread -> row=tid>>3,
  // chunk=tid&7 (and row+64). Inverse swizzle on the SOURCE column.
  const int sr = tid >> 3;                        // 0..63
  const int sc = (((tid & 7) ^ (sr & 7)) * 8);    // inverse-swizzled source col

  auto stage = [&](int buf, int kk) {
    gload_lds16(Ab + (size_t)sr * Kfull + kk + sc,        &As[buf][tid * 8]);
    gload_lds16(Bb + (size_t)sr * Kfull + kk + sc,        &Bs[buf][tid * 8]);
    gload_lds16(Ab + (size_t)(sr + 64) * Kfull + kk + sc, &As[buf][(tid + 512) * 8]);
    gload_lds16(Bb + (size_t)(sr + 64) * Kfull + kk + sc, &Bs[buf][(tid + 512) * 8]);
  };

  stage(0, 0);
  __syncthreads();

  const int nk = Keff >> 6;
  for (int t = 0; t < nk; ++t) {
    const int buf = t & 1;
    if (t + 1 < nk) stage(buf ^ 1, (t + 1) * 64);
#pragma unroll
    for (int s = 0; s < 2; s++) {                 // two K=32 slices per tile
      bf16x8 af[4], bfr[2];
#pragma unroll
      for (int i = 0; i < 4; i++) {
        const int row = wr + i * 16 + lr;
        af[i] = *(const bf16x8*)(&As[buf][row * 64 + (((s * 4 + lg) ^ (row & 7)) * 8)]);
      }
#pragma unroll
      for (int j = 0; j < 2; j++) {
        const int row = wc + j * 16 + lr;
        bfr[j] = *(const bf16x8*)(&Bs[buf][row * 64 + (((s * 4 + lg) ^ (row & 7)) * 8)]);
      }
#pragma unroll
      for (int i = 0; i < 4; i++)
#pragma unroll
        for (int j = 0; j < 2; j++)
          acc[i][j] = __builtin_amdgcn_mfma_f32_16x16x32_bf16(af[i], bfr[j], acc[i][j], 0, 0, 0);
    }
    __syncthreads();
  }

  const int rg = (lane >> 4) * 4;
#pragma unroll
  for (int j = 0; j < 2; j++) {
    const int col = n0 + wc + j * 16 + lr;
    const float bv = (bias && kb == 0) ? bias[col] : 0.0f;
#pragma unroll
    for (int i = 0; i < 4; i++) {
#pragma unroll
      for (int r = 0; r < 4; r++) {
        const int row = m0 + wr + i * 16 + rg + r;
        C[(size_t)row * N + col] = (bf16_t)(acc[i][j][r] + bv);
      }
    }
  }
}

// ------------------------------------------------------------------
// Flash attention (swapped QK^T): S^T = mfma(K,Q), per-lane scalar
// online softmax with defer-max, cvt_pk P-packing, K/V^T LDS dbuf
// with XOR swizzle, setprio around MFMA.  (V must stay LDS-staged —
// direct L2 reads serialize, +100% dur, round-13 evidence.)
// ------------------------------------------------------------------
__global__ __launch_bounds__(512)
void k_attn(const bf16_t* __restrict__ qkv, const bf16_t* __restrict__ vt,
            bf16_t* __restrict__ out, const int* __restrict__ bflag)
{
  if (bflag[blockIdx.x >> 3]) return;
  const int bh = blockIdx.x;
  const int qt = blockIdx.y;
  const int b = bh >> 3, h = bh & 7;
  const int tid = threadIdx.x, lane = tid & 63, wave = tid >> 6;
  const int lr = lane & 15, lg = lane >> 4;

  __shared__ bf16_t Ks[2][4096];
  __shared__ bf16_t Vs[2][4096];
  __shared__ bf16_t Pl[8][16][68];

  const size_t RS = 1536;
  const bf16_t* Qb = qkv + ((size_t)(b * 1024 + qt * 128)) * RS + h * 64;
  const bf16_t* Kb = qkv + ((size_t)(b * 1024)) * RS + 512 + h * 64;
  const bf16_t* Vt = vt + (size_t)bh * 64 * 1024;

  const float SC = 0.125f * 1.4426950408889634f;
  bf16x8 qf[2];
#pragma unroll
  for (int ks = 0; ks < 2; ks++) {
    bf16x8 q = *(const bf16x8*)(Qb + (size_t)(wave * 16 + lr) * RS + lg * 8 + ks * 32);
#pragma unroll
    for (int u = 0; u < 8; u++) q[u] = (bf16_t)((float)q[u] * SC);
    qf[ks] = q;
  }

  f32x4 o[4] = {};
  float m_ = -1e30f, ls_ = 0.0f;     // per-lane: q-row = wave*16 + lane&15

  auto stage = [&](int buf, int kv) {
    const int c = tid;
    const int r = c >> 3;
    const int ce = (c & 7) * 8;
    const int cs = ce ^ ((r & 7) << 3);
    gload_lds16(Kb + (size_t)(kv * 64 + r) * RS + cs, &Ks[buf][c * 8]);
    gload_lds16(Vt + (size_t)r * 1024 + kv * 64 + cs, &Vs[buf][c * 8]);
  };

  stage(0, 0);
  __syncthreads();

  const int sw = (lr & 7) << 3;

  for (int kv = 0; kv < 16; kv++) {
    const int buf = kv & 1;
    if (kv < 15) stage(buf ^ 1, kv + 1);

    f32x4 sfr[4];
    __builtin_amdgcn_s_setprio(1);
#pragma unroll
    for (int j = 0; j < 4; j++) {
      f32x4 z = {};
#pragma unroll
      for (int ks = 0; ks < 2; ks++) {
        bf16x8 kf = *(const bf16x8*)(&Ks[buf][(j * 16 + lr) * 64 + ((lg * 8 + ks * 32) ^ sw)]);
        z = __builtin_amdgcn_mfma_f32_16x16x32_bf16(kf, qf[ks], z, 0, 0, 0);
      }
      sfr[j] = z;
    }
    __builtin_amdgcn_s_setprio(0);

    float px = sfr[0][0];
#pragma unroll
    for (int j = 0; j < 4; j++)
#pragma unroll
      for (int r = 0; r < 4; r++) px = fmaxf(px, sfr[j][r]);
    if (!__all(px <= m_ + 8.0f)) {
      float mx = fmaxf(px, __shfl_xor(px, 16, 64));
      mx = fmaxf(mx, __shfl_xor(mx, 32, 64));
      mx = fmaxf(mx, m_);
      const float al = __builtin_amdgcn_exp2f(m_ - mx);
      m_ = mx;
      ls_ *= al;
      float aq[4];
#pragma unroll
      for (int r = 0; r < 4; r++) aq[r] = __shfl(al, lg * 4 + r, 64);
#pragma unroll
      for (int j = 0; j < 4; j++)
#pragma unroll
        for (int r = 0; r < 4; r++) o[j][r] *= aq[r];
    }

    float ps = 0.0f;
#pragma unroll
    for (int j = 0; j < 4; j++) {
      const float p0 = __builtin_amdgcn_exp2f(sfr[j][0] - m_);
      const float p1 = __builtin_amdgcn_exp2f(sfr[j][1] - m_);
      const float p2 = __builtin_amdgcn_exp2f(sfr[j][2] - m_);
      const float p3 = __builtin_amdgcn_exp2f(sfr[j][3] - m_);
      ps += (p0 + p1) + (p2 + p3);
      unsigned lo, hi;
      asm("v_cvt_pk_bf16_f32 %0, %1, %2" : "=v"(lo) : "v"(p0), "v"(p1));
      asm("v_cvt_pk_bf16_f32 %0, %1, %2" : "=v"(hi) : "v"(p2), "v"(p3));
      uint2 w; w.x = lo; w.y = hi;
      *(uint2*)(&Pl[wave][lr][j * 16 + lg * 4]) = w;
    }
    ls_ += ps;

    __builtin_amdgcn_s_setprio(1);
#pragma unroll
    for (int ks = 0; ks < 2; ks++) {
      bf16x8 pa = *(const bf16x8*)(&Pl[wave][lr][lg * 8 + ks * 32]);
#pragma unroll
      for (int j = 0; j < 4; j++) {
        bf16x8 vb = *(const bf16x8*)(&Vs[buf][(j * 16 + lr) * 64 + ((lg * 8 + ks * 32) ^ sw)]);
        o[j] = __builtin_amdgcn_mfma_f32_16x16x32_bf16(pa, vb, o[j], 0, 0, 0);
      }
    }
    __builtin_amdgcn_s_setprio(0);

    __syncthreads();
  }

  ls_ += __shfl_xor(ls_, 16, 64);
  ls_ += __shfl_xor(ls_, 32, 64);
  float lsq[4];
#pragma unroll
  for (int r = 0; r < 4; r++) lsq[r] = __shfl(ls_, lg * 4 + r, 64);

  const size_t orow = (size_t)(b * 1024 + qt * 128 + wave * 16 + lg * 4);
#pragma unroll
  for (int j = 0; j < 4; j++)
#pragma unroll
    for (int r = 0; r < 4; r++)
      out[(orow + r) * 512 + h * 64 + j * 16 + lr] = (bf16_t)(o[j][r] / lsq[r]);
}

// ------------------------------------------------------------------
// Step 0 top: x = state + pos + ts[0] (bf16 out only — xB doubles as
// the LN1 residual); p = sigmoid(x . p_w + p_b); ACT halting update.
// ------------------------------------------------------------------
__global__ __launch_bounds__(256)
void k_poshalt(const float* __restrict__ state, bf16_t* __restrict__ xbf,
               const float* __restrict__ pos, const float* __restrict__ ts,
               const float* __restrict__ pw, const float* __restrict__ pb,
               float* __restrict__ hp, float* __restrict__ rem, float* __restrict__ uw)
{
  const int row = blockIdx.x;
  const int l = row & 1023;
  const int t = threadIdx.x;
  const size_t base = (size_t)row * 512;
  float v0 = state[base + t]       + pos[l * 512 + t]       + ts[t];
  float v1 = state[base + 256 + t] + pos[l * 512 + 256 + t] + ts[256 + t];
  xbf[base + t] = (bf16_t)v0; xbf[base + 256 + t] = (bf16_t)v1;

  float d = v0 * pw[t] + v1 * pw[256 + t];
#pragma unroll
  for (int mk = 1; mk < 64; mk <<= 1) d += __shfl_xor(d, mk, 64);
  __shared__ float part[4];
  if ((t & 63) == 0) part[t >> 6] = d;
  __syncthreads();
  if (t == 0) {
    const float z = part[0] + part[1] + part[2] + part[3] + pb[0];
    const float p = 1.0f / (1.0f + expf(-z));
    float h = 0.0f, rm = 0.0f;
    const float cond = p;
    const float nh = (cond > 0.9f) ? 1.0f : 0.0f;
    const float st = (cond <= 0.9f) ? 1.0f : 0.0f;
    h += p * st;
    rm += nh * (1.0f - h);
    h += nh * rm;
    hp[row] = h; rem[row] = rm;
    uw[row] = p * st + nh * rm;
  }
}

// ------------------------------------------------------------------
// Post-attn LN: y = LayerNorm(xB + o0 + o1)  (all bf16; o0/o1 are the
// O-proj split-K halves); write y bf16 only.
// ------------------------------------------------------------------
__global__ __launch_bounds__(256)
void k_addln1(const bf16_t* __restrict__ xb, const bf16_t* __restrict__ o0,
              const bf16_t* __restrict__ o1,
              const float* __restrict__ g, const float* __restrict__ be,
              bf16_t* __restrict__ ybf, const int* __restrict__ bflag)
{
  if (bflag[blockIdx.x >> 10]) return;
  const int row = blockIdx.x, t = threadIdx.x;
  const size_t base = (size_t)row * 512 + 2 * t;
  bf16x2 xv = *(const bf16x2*)(xb + base);
  bf16x2 a0 = *(const bf16x2*)(o0 + base);
  bf16x2 a1 = *(const bf16x2*)(o1 + base);
  const float v0 = (float)xv[0] + (float)a0[0] + (float)a1[0];
  const float v1 = (float)xv[1] + (float)a0[1] + (float)a1[1];
  float s1 = v0 + v1, s2 = v0 * v0 + v1 * v1;
#pragma unroll
  for (int mk = 1; mk < 64; mk <<= 1) { s1 += __shfl_xor(s1, mk, 64); s2 += __shfl_xor(s2, mk, 64); }
  __shared__ float p1[4], p2[4];
  if ((t & 63) == 0) { p1[t >> 6] = s1; p2[t >> 6] = s2; }
  __syncthreads();
  s1 = p1[0] + p1[1] + p1[2] + p1[3];
  s2 = p2[0] + p2[1] + p2[2] + p2[3];
  const float mean = s1 * (1.0f / 512.0f);
  const float var  = s2 * (1.0f / 512.0f) - mean * mean;
  const float ri = rsqrtf(var + 1e-5f);
  f32x2 gv = *(const f32x2*)(g + 2 * t);
  f32x2 bv = *(const f32x2*)(be + 2 * t);
  bf16x2 yo;
  yo[0] = (bf16_t)((v0 - mean) * ri * gv[0] + bv[0]);
  yo[1] = (bf16_t)((v1 - mean) * ri * gv[1] + bv[1]);
  *(bf16x2*)(ybf + base) = yo;
}

// ------------------------------------------------------------------
// Fused bottom-of-step: y = LN(x1B + pA + pB) (bf16 inputs);
// prev = y*uw + prev*(1-uw); then NEXT step's pos/ts add + halting
// (writes only xB, the bf16 state that doubles as next residual).
// ------------------------------------------------------------------
template <bool LAST>
__global__ __launch_bounds__(256)
void k_lnhalt(const bf16_t* __restrict__ x1b, const bf16_t* __restrict__ pA,
              const bf16_t* __restrict__ pB,
              const float* __restrict__ g, const float* __restrict__ be,
              const float* __restrict__ pos, const float* __restrict__ ts, int nstep,
              const float* __restrict__ pw, const float* __restrict__ pb,
              bf16_t* __restrict__ xbf,
              float* __restrict__ hp, float* __restrict__ rem, float* __restrict__ uw,
              float* __restrict__ prev, int step, const int* __restrict__ bflag)
{
  if (bflag[blockIdx.x >> 10]) return;
  const int row = blockIdx.x, t = threadIdx.x;
  const int l = row & 1023;
  const size_t base = (size_t)row * 512 + 2 * t;
  bf16x2 xv = *(const bf16x2*)(x1b + base);
  bf16x2 av = *(const bf16x2*)(pA + base);
  bf16x2 bv2 = *(const bf16x2*)(pB + base);
  const float a0 = (float)xv[0] + (float)av[0] + (float)bv2[0];
  const float a1 = (float)xv[1] + (float)av[1] + (float)bv2[1];
  float s1 = a0 + a1, s2 = a0 * a0 + a1 * a1;
#pragma unroll
  for (int mk = 1; mk < 64; mk <<= 1) { s1 += __shfl_xor(s1, mk, 64); s2 += __shfl_xor(s2, mk, 64); }
  __shared__ float p1[4], p2[4], pd[4];
  if ((t & 63) == 0) { p1[t >> 6] = s1; p2[t >> 6] = s2; }
  __syncthreads();
  s1 = p1[0] + p1[1] + p1[2] + p1[3];
  s2 = p2[0] + p2[1] + p2[2] + p2[3];
  const float mean = s1 * (1.0f / 512.0f);
  const float var  = s2 * (1.0f / 512.0f) - mean * mean;
  const float ri = rsqrtf(var + 1e-5f);
  f32x2 gv = *(const f32x2*)(g + 2 * t);
  f32x2 bev = *(const f32x2*)(be + 2 * t);
  const float y0 = (a0 - mean) * ri * gv[0] + bev[0];
  const float y1 = (a1 - mean) * ri * gv[1] + bev[1];

  const float w = uw[row];
  if (step == 0) {
    f32x2 np; np[0] = y0 * w; np[1] = y1 * w;
    *(f32x2*)(prev + base) = np;
  } else if (w != 0.0f) {
    f32x2 pv = *(const f32x2*)(prev + base);
    f32x2 np;
    np[0] = y0 * w + pv[0] * (1.0f - w);
    np[1] = y1 * w + pv[1] * (1.0f - w);
    *(f32x2*)(prev + base) = np;
  }

  if (LAST) return;

  f32x2 pp = *(const f32x2*)(pos + l * 512 + 2 * t);
  f32x2 tv = *(const f32x2*)(ts + nstep * 512 + 2 * t);
  const float v0 = y0 + pp[0] + tv[0];
  const float v1 = y1 + pp[1] + tv[1];
  bf16x2 xo; xo[0] = (bf16_t)v0; xo[1] = (bf16_t)v1;
  *(bf16x2*)(xbf + base) = xo;

  f32x2 wv = *(const f32x2*)(pw + 2 * t);
  float d = v0 * wv[0] + v1 * wv[1];
#pragma unroll
  for (int mk = 1; mk < 64; mk <<= 1) d += __shfl_xor(d, mk, 64);
  if ((t & 63) == 0) pd[t >> 6] = d;
  __syncthreads();
  if (t == 0) {
    const float z = pd[0] + pd[1] + pd[2] + pd[3] + pb[0];
    const float p = 1.0f / (1.0f + expf(-z));
    float h  = hp[row];
    float rm = rem[row];
    const float still0 = (h < 1.0f) ? 1.0f : 0.0f;
    const float cond = h + p * still0;
    const float nh = (cond > 0.9f) ? still0 : 0.0f;
    const float st = (cond <= 0.9f) ? still0 : 0.0f;
    h += p * st;
    rm += nh * (1.0f - h);
    h += nh * rm;
    hp[row] = h; rem[row] = rm;
    uw[row] = p * st + nh * rm;
  }
}

// ------------------------------------------------------------------
// Per-batch dead detector: block b sets bflag[b]=1 once its 1024 rows
// all have hp >= 1 AND uw == 0. Monotone (never unset).
// ------------------------------------------------------------------
__global__ __launch_bounds__(256)
void k_flag(const float* __restrict__ hp, const float* __restrict__ uw,
            int* __restrict__ bflag)
{
  const int b = blockIdx.x;
  if (bflag[b]) return;
  const int t = threadIdx.x;
  const int base = b * 1024;
  float mn = 1e30f, mxw = 0.0f;
  {
    f32x4 v = *(const f32x4*)(hp + base + t * 4);
    f32x4 u = *(const f32x4*)(uw + base + t * 4);
#pragma unroll
    for (int q = 0; q < 4; q++) { mn = fminf(mn, v[q]); mxw = fmaxf(mxw, u[q]); }
  }
#pragma unroll
  for (int mk = 1; mk < 64; mk <<= 1) {
    mn = fminf(mn, __shfl_xor(mn, mk, 64));
    mxw = fmaxf(mxw, __shfl_xor(mxw, mk, 64));
  }
  __shared__ float part[4], partw[4];
  if ((t & 63) == 0) { part[t >> 6] = mn; partw[t >> 6] = mxw; }
  __syncthreads();
  if (t == 0) {
    mn = fminf(fminf(part[0], part[1]), fminf(part[2], part[3]));
    mxw = fmaxf(fmaxf(partw[0], partw[1]), fmaxf(partw[2], partw[3]));
    if (mn >= 1.0f && mxw == 0.0f) bflag[b] = 1;
  }
}

__global__ void k_zeroflag(int* __restrict__ bflag)
{
  if (threadIdx.x < 8) bflag[threadIdx.x] = 0;
}

// ------------------------------------------------------------------
__global__ void k_pos_ts(float* __restrict__ pos, float* __restrict__ ts,
                         const int* __restrict__ outer)
{
  const int idx = blockIdx.x * 256 + threadIdx.x;
  const int l = idx >> 9, i = idx & 511;
  const float dt = expf((float)(i & ~1) * (-9.210340371976184f / 512.0f));
  const float a = (float)l * dt;
  pos[idx] = (i & 1) ? cosf(a) : sinf(a);
  if (l < 6) {
    const int gidx = 6 * outer[0] + l;
    const float a2 = (float)gidx * dt;
    ts[l * 512 + i] = (i & 1) ? cosf(a2) : sinf(a2);
  }
}

__global__ void k_f2b(const float* __restrict__ in, bf16_t* __restrict__ out, int n)
{
  const int i = blockIdx.x * 256 + threadIdx.x;
  if (i < n) out[i] = (bf16_t)in[i];
}

__global__ void k_copy(const float* __restrict__ in, float* __restrict__ out, int n)
{
  const int i = blockIdx.x * 256 + threadIdx.x;
  if (i < n) out[i] = in[i];
}

// ------------------------------------------------------------------
extern "C" void kernel_launch(void* const* d_in, const int* in_sizes, int n_in,
                              void* d_out, int out_size, void* d_ws, size_t ws_size,
                              hipStream_t stream)
{
  const float* state = (const float*)d_in[0];
  const int*   outer = (const int*)d_in[1];
  const float* p_w   = (const float*)d_in[2];
  const float* p_b   = (const float*)d_in[3];
  const float* wq = (const float*)d_in[4];
  const float* bq = (const float*)d_in[5];
  const float* wk = (const float*)d_in[6];
  const float* bk = (const float*)d_in[7];
  const float* wv = (const float*)d_in[8];
  const float* bv = (const float*)d_in[9];
  const float* wo = (const float*)d_in[10];
  const float* bo = (const float*)d_in[11];
  const float* w1 = (const float*)d_in[12];
  const float* b1 = (const float*)d_in[13];
  const float* w2 = (const float*)d_in[14];
  const float* b2 = (const float*)d_in[15];
  const float* ln1g = (const float*)d_in[16];
  const float* ln1b = (const float*)d_in[17];
  const float* ln2g = (const float*)d_in[18];
  const float* ln2b = (const float*)d_in[19];
  float* prev = (float*)d_out;

  char* cur = (char*)d_ws;
  auto take = [&](size_t n) { char* p = cur; cur += (n + 255) & ~(size_t)255; return p; };
  float*  pos   = (float*) take((size_t)1024 * 512 * 4);
  float*  ts    = (float*) take(6 * 512 * 4);
  bf16_t* wqkvB = (bf16_t*)take((size_t)1536 * 512 * 2);
  bf16_t* woB   = (bf16_t*)take((size_t)512 * 512 * 2);
  bf16_t* w1B   = (bf16_t*)take((size_t)2048 * 512 * 2);
  bf16_t* w2B   = (bf16_t*)take((size_t)512 * 2048 * 2);
  float*  bqkv  = (float*) take(1536 * 4);
  bf16_t* x1B   = (bf16_t*)take((size_t)8192 * 512 * 2);  // LN1 output
  bf16_t* pA    = (bf16_t*)take((size_t)8192 * 512 * 2);  // O-proj half1, then FFN2 half0
  char*   tmp   = take((size_t)8192 * 512 * 2);           // vt, then O-proj half0
  bf16_t* attnO = (bf16_t*)take((size_t)8192 * 512 * 2);  // attn out, then FFN2 half1
  float*  hp    = (float*) take(8192 * 4);
  float*  rem   = (float*) take(8192 * 4);
  float*  uw    = (float*) take(8192 * 4);
  int*    bflag = (int*)   take(8 * 4);
  char*   region = take((size_t)8192 * 2048 * 2);
  bf16_t* xB  = (bf16_t*)region;                            // bf16 state (QKV input + LN1 residual)
  bf16_t* qkv = (bf16_t*)(region + (size_t)8192 * 512 * 2); // Q|K cols live, V garbage
  bf16_t* hB  = (bf16_t*)region;                            // FFN1 out (overwrites xB+qkv)
  bf16_t* vt  = (bf16_t*)tmp;                               // V^T, written by QKV epilogue
  bf16_t* o0  = (bf16_t*)tmp;                               // O-proj split-K half0 (after attn)
  bf16_t* o1  = pA;                                         // O-proj split-K half1
  bf16_t* pB  = attnO;                                      // FFN2 half1 (after O-proj)

  // ---- precompute ----
  k_zeroflag<<<dim3(1), dim3(64), 0, stream>>>(bflag);
  k_pos_ts<<<dim3(2048), dim3(256), 0, stream>>>(pos, ts, outer);
  k_f2b<<<dim3(1024), dim3(256), 0, stream>>>(wq, wqkvB,               512 * 512);
  k_f2b<<<dim3(1024), dim3(256), 0, stream>>>(wk, wqkvB + 512 * 512,   512 * 512);
  k_f2b<<<dim3(1024), dim3(256), 0, stream>>>(wv, wqkvB + 1024 * 512,  512 * 512);
  k_f2b<<<dim3(1024), dim3(256), 0, stream>>>(wo, woB,                 512 * 512);
  k_f2b<<<dim3(4096), dim3(256), 0, stream>>>(w1, w1B,                 2048 * 512);
  k_f2b<<<dim3(4096), dim3(256), 0, stream>>>(w2, w2B,                 512 * 2048);
  k_copy<<<dim3(2), dim3(256), 0, stream>>>(bq, bqkv,        512);
  k_copy<<<dim3(2), dim3(256), 0, stream>>>(bk, bqkv + 512,  512);
  k_copy<<<dim3(2), dim3(256), 0, stream>>>(bv, bqkv + 1024, 512);

  // step 0 top: xB = bf16(state + pos + ts[0]); halting gate
  k_poshalt<<<dim3(8192), dim3(256), 0, stream>>>(state, xB, pos, ts, p_w, p_b, hp, rem, uw);

  // ---- 6 hops ----
  for (int step = 0; step < 6; step++) {
    gemm_bt<false, true ><<<dim3(64, 12), dim3(256), 0, stream>>>(xB, wqkvB, bqkv, qkv, vt, 8192, 1536, 512, bflag);
    k_attn<<<dim3(64, 8), dim3(512), 0, stream>>>(qkv, vt, attnO, bflag);
    // O-proj split-K=2: half0 -> o0 (+bias), half1 -> o1
    gemm_bt512<<<dim3(64, 4, 2), dim3(512), 0, stream>>>(attnO, woB, bo, o0, o1, 8192, 512, 512, 256, bflag);
    k_addln1<<<dim3(8192), dim3(256), 0, stream>>>(xB, o0, o1, ln1g, ln1b, x1B, bflag);
    gemm_bt<true, false><<<dim3(64, 16), dim3(256), 0, stream>>>(x1B, w1B, b1, hB, nullptr, 8192, 2048, 512, bflag);
    // FFN2 split-K=2: half0 -> pA (+bias), half1 -> pB
    gemm_bt512<<<dim3(64, 4, 2), dim3(512), 0, stream>>>(hB, w2B, b2, pA, pB, 8192, 512, 2048, 1024, bflag);
    if (step < 5) {
      k_lnhalt<false><<<dim3(8192), dim3(256), 0, stream>>>(x1B, pA, pB, ln2g, ln2b, pos, ts, step + 1,
                                                            p_w, p_b, xB, hp, rem, uw, prev, step, bflag);
      k_flag<<<dim3(8), dim3(256), 0, stream>>>(hp, uw, bflag);
    } else {
      k_lnhalt<true><<<dim3(8192), dim3(256), 0, stream>>>(x1B, pA, pB, ln2g, ln2b, pos, ts, 0,
                                                           p_w, p_b, xB, hp, rem, uw, prev, step, bflag);
    }
  }
}

// Round 16
// 585.253 us; speedup vs baseline: 1.3824x; 1.0673x over previous
//
#include <hip/hip_runtime.h>
#include <hip/hip_bf16.h>

typedef __bf16 bf16_t;
typedef __bf16 bf16x8 __attribute__((ext_vector_type(8)));
typedef __bf16 bf16x4 __attribute__((ext_vector_type(4)));
typedef __bf16 bf16x2 __attribute__((ext_vector_type(2)));
typedef float  f32x4  __attribute__((ext_vector_type(4)));
typedef float  f32x2  __attribute__((ext_vector_type(2)));
typedef float  f32x8  __attribute__((ext_vector_type(8)));

static __device__ __forceinline__ void gload_lds16(const void* g, void* l) {
  __builtin_amdgcn_global_load_lds((const __attribute__((address_space(1))) void*)g,
                                   (__attribute__((address_space(3))) void*)l, 16, 0, 0);
}

// LDS chunk swizzles (rule #21: linear gload_lds dest + inverse-swizzled
// global source + swizzled ds_read):
//   [rows][64] bf16 tiles (128B rows): chunk' = chunk ^ (row&7)
//   [rows][64] attn tiles: elem-level  col' = col ^ ((row&7)<<3)
// Per-batch dead flags: bflag[b]==1 once all 1024 positions of batch b have
// halted (hp>=1) AND uw==0 -> that batch's remaining compute is provably
// dead w.r.t. prev (attention never mixes across batches). Bit-exact skip.

// ------------------------------------------------------------------
// Unified GEMM  C = A*B^T (+bias; RELU opt), bf16 out. 128x128 tile,
// BK=64, 512 threads / 8 waves (2x4), wave = 64x32 (acc 4x2), 2-phase
// dbuf (64KB LDS -> 2 blocks/CU), split-K via gridDim.z (half k -> Ck,
// bias folded into half 0 only). Keff must be a multiple of 64.
// VT=true (QKV): output tiles with n0>=1024 are V columns -> written
// TRANSPOSED into vt (per (b,h): d x key); row-major write skipped.
// M-tiles (128 rows) align with batches: batch = blockIdx.x>>3.
// Used for: QKV (N=1536,z=1,VT), O-proj (z=2,Keff=256),
// FFN1 (N=2048,RELU), FFN2 (z=2,Keff=1024).
// ------------------------------------------------------------------
template <bool RELU, bool VT>
__global__ __launch_bounds__(512)
void gemm512(const bf16_t* __restrict__ A, const bf16_t* __restrict__ B,
             const float* __restrict__ bias, bf16_t* __restrict__ C0,
             bf16_t* __restrict__ C1, bf16_t* __restrict__ vt,
             int M, int N, int Kfull, int Keff, const int* __restrict__ bflag)
{
  if (bflag[blockIdx.x >> 3]) return;
  __shared__ bf16_t As[2][128 * 64];
  __shared__ bf16_t Bs[2][128 * 64];
  const int tid = threadIdx.x;
  const int lane = tid & 63, wave = tid >> 6;
  const int wr = (wave >> 2) * 64, wc = (wave & 3) * 32;
  const int lr = lane & 15, lg = lane >> 4;
  const int m0 = blockIdx.x * 128, n0 = blockIdx.y * 128;
  const int kb = blockIdx.z;

  const bf16_t* Ab = A + (size_t)m0 * Kfull + (size_t)kb * Keff;
  const bf16_t* Bb = B + (size_t)n0 * Kfull + (size_t)kb * Keff;
  bf16_t* C = kb ? C1 : C0;

  f32x4 acc[4][2] = {};

  // staging: rows of 64 cols = 8 chunks of 8 elems; thread -> row=tid>>3,
  // chunk=tid&7 (and row+64). Inverse swizzle on the SOURCE column.
  const int sr = tid >> 3;                        // 0..63
  const int sc = (((tid & 7) ^ (sr & 7)) * 8);    // inverse-swizzled source col

  auto stage = [&](int buf, int kk) {
    gload_lds16(Ab + (size_t)sr * Kfull + kk + sc,        &As[buf][tid * 8]);
    gload_lds16(Bb + (size_t)sr * Kfull + kk + sc,        &Bs[buf][tid * 8]);
    gload_lds16(Ab + (size_t)(sr + 64) * Kfull + kk + sc, &As[buf][(tid + 512) * 8]);
    gload_lds16(Bb + (size_t)(sr + 64) * Kfull + kk + sc, &Bs[buf][(tid + 512) * 8]);
  };

  stage(0, 0);
  __syncthreads();

  const int nk = Keff >> 6;
  for (int t = 0; t < nk; ++t) {
    const int buf = t & 1;
    if (t + 1 < nk) stage(buf ^ 1, (t + 1) * 64);
#pragma unroll
    for (int s = 0; s < 2; s++) {                 // two K=32 slices per tile
      bf16x8 af[4], bfr[2];
#pragma unroll
      for (int i = 0; i < 4; i++) {
        const int row = wr + i * 16 + lr;
        af[i] = *(const bf16x8*)(&As[buf][row * 64 + (((s * 4 + lg) ^ (row & 7)) * 8)]);
      }
#pragma unroll
      for (int j = 0; j < 2; j++) {
        const int row = wc + j * 16 + lr;
        bfr[j] = *(const bf16x8*)(&Bs[buf][row * 64 + (((s * 4 + lg) ^ (row & 7)) * 8)]);
      }
#pragma unroll
      for (int i = 0; i < 4; i++)
#pragma unroll
        for (int j = 0; j < 2; j++)
          acc[i][j] = __builtin_amdgcn_mfma_f32_16x16x32_bf16(af[i], bfr[j], acc[i][j], 0, 0, 0);
    }
    __syncthreads();
  }

  const int rg = (lane >> 4) * 4;
  if (VT && n0 >= 1024) {
    // V columns: write transposed vt[(b*512 + h*64 + d)][key], 4 keys/store
#pragma unroll
    for (int j = 0; j < 2; j++) {
      const int col = n0 + wc + j * 16 + lr;      // 1024..1535
      const float bv = bias[col];
      const int hd = col - 1024;                  // h*64 + d
#pragma unroll
      for (int i = 0; i < 4; i++) {
        const int row0 = m0 + wr + i * 16 + rg;   // token index (mult of 4)
        const int bb = row0 >> 10, key = row0 & 1023;
        bf16x4 q;
#pragma unroll
        for (int r = 0; r < 4; r++) q[r] = (bf16_t)(acc[i][j][r] + bv);
        *(bf16x4*)(vt + ((size_t)bb * 512 + hd) * 1024 + key) = q;
      }
    }
  } else {
#pragma unroll
    for (int j = 0; j < 2; j++) {
      const int col = n0 + wc + j * 16 + lr;
      const float bv = (bias && kb == 0) ? bias[col] : 0.0f;
#pragma unroll
      for (int i = 0; i < 4; i++) {
#pragma unroll
        for (int r = 0; r < 4; r++) {
          const int row = m0 + wr + i * 16 + rg + r;
          float v = acc[i][j][r] + bv;
          if (RELU) v = fmaxf(v, 0.0f);
          C[(size_t)row * N + col] = (bf16_t)v;
        }
      }
    }
  }
}

// ------------------------------------------------------------------
// Flash attention (swapped QK^T): S^T = mfma(K,Q), per-lane scalar
// online softmax with defer-max, cvt_pk P-packing, K/V^T LDS dbuf
// with XOR swizzle, setprio around MFMA.  (V must stay LDS-staged —
// direct L2 reads serialize, +100% dur, round-13 evidence.)
// ------------------------------------------------------------------
__global__ __launch_bounds__(512)
void k_attn(const bf16_t* __restrict__ qkv, const bf16_t* __restrict__ vt,
            bf16_t* __restrict__ out, const int* __restrict__ bflag)
{
  if (bflag[blockIdx.x >> 3]) return;
  const int bh = blockIdx.x;
  const int qt = blockIdx.y;
  const int b = bh >> 3, h = bh & 7;
  const int tid = threadIdx.x, lane = tid & 63, wave = tid >> 6;
  const int lr = lane & 15, lg = lane >> 4;

  __shared__ bf16_t Ks[2][4096];
  __shared__ bf16_t Vs[2][4096];
  __shared__ bf16_t Pl[8][16][68];

  const size_t RS = 1536;
  const bf16_t* Qb = qkv + ((size_t)(b * 1024 + qt * 128)) * RS + h * 64;
  const bf16_t* Kb = qkv + ((size_t)(b * 1024)) * RS + 512 + h * 64;
  const bf16_t* Vt = vt + (size_t)bh * 64 * 1024;

  const float SC = 0.125f * 1.4426950408889634f;
  bf16x8 qf[2];
#pragma unroll
  for (int ks = 0; ks < 2; ks++) {
    bf16x8 q = *(const bf16x8*)(Qb + (size_t)(wave * 16 + lr) * RS + lg * 8 + ks * 32);
#pragma unroll
    for (int u = 0; u < 8; u++) q[u] = (bf16_t)((float)q[u] * SC);
    qf[ks] = q;
  }

  f32x4 o[4] = {};
  float m_ = -1e30f, ls_ = 0.0f;     // per-lane: q-row = wave*16 + lane&15

  auto stage = [&](int buf, int kv) {
    const int c = tid;
    const int r = c >> 3;
    const int ce = (c & 7) * 8;
    const int cs = ce ^ ((r & 7) << 3);
    gload_lds16(Kb + (size_t)(kv * 64 + r) * RS + cs, &Ks[buf][c * 8]);
    gload_lds16(Vt + (size_t)r * 1024 + kv * 64 + cs, &Vs[buf][c * 8]);
  };

  stage(0, 0);
  __syncthreads();

  const int sw = (lr & 7) << 3;

  for (int kv = 0; kv < 16; kv++) {
    const int buf = kv & 1;
    if (kv < 15) stage(buf ^ 1, kv + 1);

    f32x4 sfr[4];
    __builtin_amdgcn_s_setprio(1);
#pragma unroll
    for (int j = 0; j < 4; j++) {
      f32x4 z = {};
#pragma unroll
      for (int ks = 0; ks < 2; ks++) {
        bf16x8 kf = *(const bf16x8*)(&Ks[buf][(j * 16 + lr) * 64 + ((lg * 8 + ks * 32) ^ sw)]);
        z = __builtin_amdgcn_mfma_f32_16x16x32_bf16(kf, qf[ks], z, 0, 0, 0);
      }
      sfr[j] = z;
    }
    __builtin_amdgcn_s_setprio(0);

    float px = sfr[0][0];
#pragma unroll
    for (int j = 0; j < 4; j++)
#pragma unroll
      for (int r = 0; r < 4; r++) px = fmaxf(px, sfr[j][r]);
    if (!__all(px <= m_ + 8.0f)) {
      float mx = fmaxf(px, __shfl_xor(px, 16, 64));
      mx = fmaxf(mx, __shfl_xor(mx, 32, 64));
      mx = fmaxf(mx, m_);
      const float al = __builtin_amdgcn_exp2f(m_ - mx);
      m_ = mx;
      ls_ *= al;
      float aq[4];
#pragma unroll
      for (int r = 0; r < 4; r++) aq[r] = __shfl(al, lg * 4 + r, 64);
#pragma unroll
      for (int j = 0; j < 4; j++)
#pragma unroll
        for (int r = 0; r < 4; r++) o[j][r] *= aq[r];
    }

    float ps = 0.0f;
#pragma unroll
    for (int j = 0; j < 4; j++) {
      const float p0 = __builtin_amdgcn_exp2f(sfr[j][0] - m_);
      const float p1 = __builtin_amdgcn_exp2f(sfr[j][1] - m_);
      const float p2 = __builtin_amdgcn_exp2f(sfr[j][2] - m_);
      const float p3 = __builtin_amdgcn_exp2f(sfr[j][3] - m_);
      ps += (p0 + p1) + (p2 + p3);
      unsigned lo, hi;
      asm("v_cvt_pk_bf16_f32 %0, %1, %2" : "=v"(lo) : "v"(p0), "v"(p1));
      asm("v_cvt_pk_bf16_f32 %0, %1, %2" : "=v"(hi) : "v"(p2), "v"(p3));
      uint2 w; w.x = lo; w.y = hi;
      *(uint2*)(&Pl[wave][lr][j * 16 + lg * 4]) = w;
    }
    ls_ += ps;

    __builtin_amdgcn_s_setprio(1);
#pragma unroll
    for (int ks = 0; ks < 2; ks++) {
      bf16x8 pa = *(const bf16x8*)(&Pl[wave][lr][lg * 8 + ks * 32]);
#pragma unroll
      for (int j = 0; j < 4; j++) {
        bf16x8 vb = *(const bf16x8*)(&Vs[buf][(j * 16 + lr) * 64 + ((lg * 8 + ks * 32) ^ sw)]);
        o[j] = __builtin_amdgcn_mfma_f32_16x16x32_bf16(pa, vb, o[j], 0, 0, 0);
      }
    }
    __builtin_amdgcn_s_setprio(0);

    __syncthreads();
  }

  ls_ += __shfl_xor(ls_, 16, 64);
  ls_ += __shfl_xor(ls_, 32, 64);
  float lsq[4];
#pragma unroll
  for (int r = 0; r < 4; r++) lsq[r] = __shfl(ls_, lg * 4 + r, 64);

  const size_t orow = (size_t)(b * 1024 + qt * 128 + wave * 16 + lg * 4);
#pragma unroll
  for (int j = 0; j < 4; j++)
#pragma unroll
    for (int r = 0; r < 4; r++)
      out[(orow + r) * 512 + h * 64 + j * 16 + lr] = (bf16_t)(o[j][r] / lsq[r]);
}

// ------------------------------------------------------------------
// Step 0 top: x = state + pos + ts[0] (bf16 out only — xB doubles as
// the LN1 residual); p = sigmoid(x . p_w + p_b); ACT halting update.
// ------------------------------------------------------------------
__global__ __launch_bounds__(256)
void k_poshalt(const float* __restrict__ state, bf16_t* __restrict__ xbf,
               const float* __restrict__ pos, const float* __restrict__ ts,
               const float* __restrict__ pw, const float* __restrict__ pb,
               float* __restrict__ hp, float* __restrict__ rem, float* __restrict__ uw)
{
  const int row = blockIdx.x;
  const int l = row & 1023;
  const int t = threadIdx.x;
  const size_t base = (size_t)row * 512;
  float v0 = state[base + t]       + pos[l * 512 + t]       + ts[t];
  float v1 = state[base + 256 + t] + pos[l * 512 + 256 + t] + ts[256 + t];
  xbf[base + t] = (bf16_t)v0; xbf[base + 256 + t] = (bf16_t)v1;

  float d = v0 * pw[t] + v1 * pw[256 + t];
#pragma unroll
  for (int mk = 1; mk < 64; mk <<= 1) d += __shfl_xor(d, mk, 64);
  __shared__ float part[4];
  if ((t & 63) == 0) part[t >> 6] = d;
  __syncthreads();
  if (t == 0) {
    const float z = part[0] + part[1] + part[2] + part[3] + pb[0];
    const float p = 1.0f / (1.0f + expf(-z));
    float h = 0.0f, rm = 0.0f;
    const float cond = p;
    const float nh = (cond > 0.9f) ? 1.0f : 0.0f;
    const float st = (cond <= 0.9f) ? 1.0f : 0.0f;
    h += p * st;
    rm += nh * (1.0f - h);
    h += nh * rm;
    hp[row] = h; rem[row] = rm;
    uw[row] = p * st + nh * rm;
  }
}

// ------------------------------------------------------------------
// Post-attn LN: y = LayerNorm(xB + o0 + o1)  (all bf16; o0/o1 are the
// O-proj split-K halves); write y bf16 only.
// ------------------------------------------------------------------
__global__ __launch_bounds__(256)
void k_addln1(const bf16_t* __restrict__ xb, const bf16_t* __restrict__ o0,
              const bf16_t* __restrict__ o1,
              const float* __restrict__ g, const float* __restrict__ be,
              bf16_t* __restrict__ ybf, const int* __restrict__ bflag)
{
  if (bflag[blockIdx.x >> 10]) return;
  const int row = blockIdx.x, t = threadIdx.x;
  const size_t base = (size_t)row * 512 + 2 * t;
  bf16x2 xv = *(const bf16x2*)(xb + base);
  bf16x2 a0 = *(const bf16x2*)(o0 + base);
  bf16x2 a1 = *(const bf16x2*)(o1 + base);
  const float v0 = (float)xv[0] + (float)a0[0] + (float)a1[0];
  const float v1 = (float)xv[1] + (float)a0[1] + (float)a1[1];
  float s1 = v0 + v1, s2 = v0 * v0 + v1 * v1;
#pragma unroll
  for (int mk = 1; mk < 64; mk <<= 1) { s1 += __shfl_xor(s1, mk, 64); s2 += __shfl_xor(s2, mk, 64); }
  __shared__ float p1[4], p2[4];
  if ((t & 63) == 0) { p1[t >> 6] = s1; p2[t >> 6] = s2; }
  __syncthreads();
  s1 = p1[0] + p1[1] + p1[2] + p1[3];
  s2 = p2[0] + p2[1] + p2[2] + p2[3];
  const float mean = s1 * (1.0f / 512.0f);
  const float var  = s2 * (1.0f / 512.0f) - mean * mean;
  const float ri = rsqrtf(var + 1e-5f);
  f32x2 gv = *(const f32x2*)(g + 2 * t);
  f32x2 bv = *(const f32x2*)(be + 2 * t);
  bf16x2 yo;
  yo[0] = (bf16_t)((v0 - mean) * ri * gv[0] + bv[0]);
  yo[1] = (bf16_t)((v1 - mean) * ri * gv[1] + bv[1]);
  *(bf16x2*)(ybf + base) = yo;
}

// ------------------------------------------------------------------
// Fused bottom-of-step: y = LN(x1B + pA + pB) (bf16 inputs);
// prev = y*uw + prev*(1-uw); then NEXT step's pos/ts add + halting
// (writes only xB, the bf16 state that doubles as next residual).
// ------------------------------------------------------------------
template <bool LAST>
__global__ __launch_bounds__(256)
void k_lnhalt(const bf16_t* __restrict__ x1b, const bf16_t* __restrict__ pA,
              const bf16_t* __restrict__ pB,
              const float* __restrict__ g, const float* __restrict__ be,
              const float* __restrict__ pos, const float* __restrict__ ts, int nstep,
              const float* __restrict__ pw, const float* __restrict__ pb,
              bf16_t* __restrict__ xbf,
              float* __restrict__ hp, float* __restrict__ rem, float* __restrict__ uw,
              float* __restrict__ prev, int step, const int* __restrict__ bflag)
{
  if (bflag[blockIdx.x >> 10]) return;
  const int row = blockIdx.x, t = threadIdx.x;
  const int l = row & 1023;
  const size_t base = (size_t)row * 512 + 2 * t;
  bf16x2 xv = *(const bf16x2*)(x1b + base);
  bf16x2 av = *(const bf16x2*)(pA + base);
  bf16x2 bv2 = *(const bf16x2*)(pB + base);
  const float a0 = (float)xv[0] + (float)av[0] + (float)bv2[0];
  const float a1 = (float)xv[1] + (float)av[1] + (float)bv2[1];
  float s1 = a0 + a1, s2 = a0 * a0 + a1 * a1;
#pragma unroll
  for (int mk = 1; mk < 64; mk <<= 1) { s1 += __shfl_xor(s1, mk, 64); s2 += __shfl_xor(s2, mk, 64); }
  __shared__ float p1[4], p2[4], pd[4];
  if ((t & 63) == 0) { p1[t >> 6] = s1; p2[t >> 6] = s2; }
  __syncthreads();
  s1 = p1[0] + p1[1] + p1[2] + p1[3];
  s2 = p2[0] + p2[1] + p2[2] + p2[3];
  const float mean = s1 * (1.0f / 512.0f);
  const float var  = s2 * (1.0f / 512.0f) - mean * mean;
  const float ri = rsqrtf(var + 1e-5f);
  f32x2 gv = *(const f32x2*)(g + 2 * t);
  f32x2 bev = *(const f32x2*)(be + 2 * t);
  const float y0 = (a0 - mean) * ri * gv[0] + bev[0];
  const float y1 = (a1 - mean) * ri * gv[1] + bev[1];

  const float w = uw[row];
  if (step == 0) {
    f32x2 np; np[0] = y0 * w; np[1] = y1 * w;
    *(f32x2*)(prev + base) = np;
  } else if (w != 0.0f) {
    f32x2 pv = *(const f32x2*)(prev + base);
    f32x2 np;
    np[0] = y0 * w + pv[0] * (1.0f - w);
    np[1] = y1 * w + pv[1] * (1.0f - w);
    *(f32x2*)(prev + base) = np;
  }

  if (LAST) return;

  f32x2 pp = *(const f32x2*)(pos + l * 512 + 2 * t);
  f32x2 tv = *(const f32x2*)(ts + nstep * 512 + 2 * t);
  const float v0 = y0 + pp[0] + tv[0];
  const float v1 = y1 + pp[1] + tv[1];
  bf16x2 xo; xo[0] = (bf16_t)v0; xo[1] = (bf16_t)v1;
  *(bf16x2*)(xbf + base) = xo;

  f32x2 wv = *(const f32x2*)(pw + 2 * t);
  float d = v0 * wv[0] + v1 * wv[1];
#pragma unroll
  for (int mk = 1; mk < 64; mk <<= 1) d += __shfl_xor(d, mk, 64);
  if ((t & 63) == 0) pd[t >> 6] = d;
  __syncthreads();
  if (t == 0) {
    const float z = pd[0] + pd[1] + pd[2] + pd[3] + pb[0];
    const float p = 1.0f / (1.0f + expf(-z));
    float h  = hp[row];
    float rm = rem[row];
    const float still0 = (h < 1.0f) ? 1.0f : 0.0f;
    const float cond = h + p * still0;
    const float nh = (cond > 0.9f) ? still0 : 0.0f;
    const float st = (cond <= 0.9f) ? still0 : 0.0f;
    h += p * st;
    rm += nh * (1.0f - h);
    h += nh * rm;
    hp[row] = h; rem[row] = rm;
    uw[row] = p * st + nh * rm;
  }
}

// ------------------------------------------------------------------
// Per-batch dead detector: block b sets bflag[b]=1 once its 1024 rows
// all have hp >= 1 AND uw == 0. Monotone (never unset).
// ------------------------------------------------------------------
__global__ __launch_bounds__(256)
void k_flag(const float* __restrict__ hp, const float* __restrict__ uw,
            int* __restrict__ bflag)
{
  const int b = blockIdx.x;
  if (bflag[b]) return;
  const int t = threadIdx.x;
  const int base = b * 1024;
  float mn = 1e30f, mxw = 0.0f;
  {
    f32x4 v = *(const f32x4*)(hp + base + t * 4);
    f32x4 u = *(const f32x4*)(uw + base + t * 4);
#pragma unroll
    for (int q = 0; q < 4; q++) { mn = fminf(mn, v[q]); mxw = fmaxf(mxw, u[q]); }
  }
#pragma unroll
  for (int mk = 1; mk < 64; mk <<= 1) {
    mn = fminf(mn, __shfl_xor(mn, mk, 64));
    mxw = fmaxf(mxw, __shfl_xor(mxw, mk, 64));
  }
  __shared__ float part[4], partw[4];
  if ((t & 63) == 0) { part[t >> 6] = mn; partw[t >> 6] = mxw; }
  __syncthreads();
  if (t == 0) {
    mn = fminf(fminf(part[0], part[1]), fminf(part[2], part[3]));
    mxw = fmaxf(fmaxf(partw[0], partw[1]), fmaxf(partw[2], partw[3]));
    if (mn >= 1.0f && mxw == 0.0f) bflag[b] = 1;
  }
}

__global__ void k_zeroflag(int* __restrict__ bflag)
{
  if (threadIdx.x < 8) bflag[threadIdx.x] = 0;
}

// ------------------------------------------------------------------
__global__ void k_pos_ts(float* __restrict__ pos, float* __restrict__ ts,
                         const int* __restrict__ outer)
{
  const int idx = blockIdx.x * 256 + threadIdx.x;
  const int l = idx >> 9, i = idx & 511;
  const float dt = expf((float)(i & ~1) * (-9.210340371976184f / 512.0f));
  const float a = (float)l * dt;
  pos[idx] = (i & 1) ? cosf(a) : sinf(a);
  if (l < 6) {
    const int gidx = 6 * outer[0] + l;
    const float a2 = (float)gidx * dt;
    ts[l * 512 + i] = (i & 1) ? cosf(a2) : sinf(a2);
  }
}

__global__ void k_f2b(const float* __restrict__ in, bf16_t* __restrict__ out, int n)
{
  const int i = blockIdx.x * 256 + threadIdx.x;
  if (i < n) out[i] = (bf16_t)in[i];
}

__global__ void k_copy(const float* __restrict__ in, float* __restrict__ out, int n)
{
  const int i = blockIdx.x * 256 + threadIdx.x;
  if (i < n) out[i] = in[i];
}

// ------------------------------------------------------------------
extern "C" void kernel_launch(void* const* d_in, const int* in_sizes, int n_in,
                              void* d_out, int out_size, void* d_ws, size_t ws_size,
                              hipStream_t stream)
{
  const float* state = (const float*)d_in[0];
  const int*   outer = (const int*)d_in[1];
  const float* p_w   = (const float*)d_in[2];
  const float* p_b   = (const float*)d_in[3];
  const float* wq = (const float*)d_in[4];
  const float* bq = (const float*)d_in[5];
  const float* wk = (const float*)d_in[6];
  const float* bk = (const float*)d_in[7];
  const float* wv = (const float*)d_in[8];
  const float* bv = (const float*)d_in[9];
  const float* wo = (const float*)d_in[10];
  const float* bo = (const float*)d_in[11];
  const float* w1 = (const float*)d_in[12];
  const float* b1 = (const float*)d_in[13];
  const float* w2 = (const float*)d_in[14];
  const float* b2 = (const float*)d_in[15];
  const float* ln1g = (const float*)d_in[16];
  const float* ln1b = (const float*)d_in[17];
  const float* ln2g = (const float*)d_in[18];
  const float* ln2b = (const float*)d_in[19];
  float* prev = (float*)d_out;

  char* cur = (char*)d_ws;
  auto take = [&](size_t n) { char* p = cur; cur += (n + 255) & ~(size_t)255; return p; };
  float*  pos   = (float*) take((size_t)1024 * 512 * 4);
  float*  ts    = (float*) take(6 * 512 * 4);
  bf16_t* wqkvB = (bf16_t*)take((size_t)1536 * 512 * 2);
  bf16_t* woB   = (bf16_t*)take((size_t)512 * 512 * 2);
  bf16_t* w1B   = (bf16_t*)take((size_t)2048 * 512 * 2);
  bf16_t* w2B   = (bf16_t*)take((size_t)512 * 2048 * 2);
  float*  bqkv  = (float*) take(1536 * 4);
  bf16_t* x1B   = (bf16_t*)take((size_t)8192 * 512 * 2);  // LN1 output
  bf16_t* pA    = (bf16_t*)take((size_t)8192 * 512 * 2);  // O-proj half1, then FFN2 half0
  char*   tmp   = take((size_t)8192 * 512 * 2);           // vt, then O-proj half0
  bf16_t* attnO = (bf16_t*)take((size_t)8192 * 512 * 2);  // attn out, then FFN2 half1
  float*  hp    = (float*) take(8192 * 4);
  float*  rem   = (float*) take(8192 * 4);
  float*  uw    = (float*) take(8192 * 4);
  int*    bflag = (int*)   take(8 * 4);
  char*   region = take((size_t)8192 * 2048 * 2);
  bf16_t* xB  = (bf16_t*)region;                            // bf16 state (QKV input + LN1 residual)
  bf16_t* qkv = (bf16_t*)(region + (size_t)8192 * 512 * 2); // Q|K cols live, V garbage
  bf16_t* hB  = (bf16_t*)region;                            // FFN1 out (overwrites xB+qkv)
  bf16_t* vt  = (bf16_t*)tmp;                               // V^T, written by QKV epilogue
  bf16_t* o0  = (bf16_t*)tmp;                               // O-proj split-K half0 (after attn)
  bf16_t* o1  = pA;                                         // O-proj split-K half1
  bf16_t* pB  = attnO;                                      // FFN2 half1 (after O-proj)

  // ---- precompute ----
  k_zeroflag<<<dim3(1), dim3(64), 0, stream>>>(bflag);
  k_pos_ts<<<dim3(2048), dim3(256), 0, stream>>>(pos, ts, outer);
  k_f2b<<<dim3(1024), dim3(256), 0, stream>>>(wq, wqkvB,               512 * 512);
  k_f2b<<<dim3(1024), dim3(256), 0, stream>>>(wk, wqkvB + 512 * 512,   512 * 512);
  k_f2b<<<dim3(1024), dim3(256), 0, stream>>>(wv, wqkvB + 1024 * 512,  512 * 512);
  k_f2b<<<dim3(1024), dim3(256), 0, stream>>>(wo, woB,                 512 * 512);
  k_f2b<<<dim3(4096), dim3(256), 0, stream>>>(w1, w1B,                 2048 * 512);
  k_f2b<<<dim3(4096), dim3(256), 0, stream>>>(w2, w2B,                 512 * 2048);
  k_copy<<<dim3(2), dim3(256), 0, stream>>>(bq, bqkv,        512);
  k_copy<<<dim3(2), dim3(256), 0, stream>>>(bk, bqkv + 512,  512);
  k_copy<<<dim3(2), dim3(256), 0, stream>>>(bv, bqkv + 1024, 512);

  // step 0 top: xB = bf16(state + pos + ts[0]); halting gate
  k_poshalt<<<dim3(8192), dim3(256), 0, stream>>>(state, xB, pos, ts, p_w, p_b, hp, rem, uw);

  // ---- 6 hops ----
  for (int step = 0; step < 6; step++) {
    // QKV (V written transposed into vt by the epilogue)
    gemm512<false, true ><<<dim3(64, 12, 1), dim3(512), 0, stream>>>(xB, wqkvB, bqkv, qkv, nullptr, vt, 8192, 1536, 512, 512, bflag);
    k_attn<<<dim3(64, 8), dim3(512), 0, stream>>>(qkv, vt, attnO, bflag);
    // O-proj split-K=2: half0 -> o0 (+bias), half1 -> o1
    gemm512<false, false><<<dim3(64, 4, 2), dim3(512), 0, stream>>>(attnO, woB, bo, o0, o1, nullptr, 8192, 512, 512, 256, bflag);
    k_addln1<<<dim3(8192), dim3(256), 0, stream>>>(xB, o0, o1, ln1g, ln1b, x1B, bflag);
    // FFN1 (+relu)
    gemm512<true, false><<<dim3(64, 16, 1), dim3(512), 0, stream>>>(x1B, w1B, b1, hB, nullptr, nullptr, 8192, 2048, 512, 512, bflag);
    // FFN2 split-K=2: half0 -> pA (+bias), half1 -> pB
    gemm512<false, false><<<dim3(64, 4, 2), dim3(512), 0, stream>>>(hB, w2B, b2, pA, pB, nullptr, 8192, 512, 2048, 1024, bflag);
    if (step < 5) {
      k_lnhalt<false><<<dim3(8192), dim3(256), 0, stream>>>(x1B, pA, pB, ln2g, ln2b, pos, ts, step + 1,
                                                            p_w, p_b, xB, hp, rem, uw, prev, step, bflag);
      k_flag<<<dim3(8), dim3(256), 0, stream>>>(hp, uw, bflag);
    } else {
      k_lnhalt<true><<<dim3(8192), dim3(256), 0, stream>>>(x1B, pA, pB, ln2g, ln2b, pos, ts, 0,
                                                           p_w, p_b, xB, hp, rem, uw, prev, step, bflag);
    }
  }
}